// Round 1
// baseline (342.741 us; speedup 1.0000x reference)
//
#include <hip/hip_runtime.h>
#include <hip/hip_bf16.h>

// Problem constants: B=2, N=2048, E=1024, H=16, D_K=64, GAMMA=1
//   tokens M = 4096, K = 1024
//
// ws layout (ushort elems), SZ = 4096*1024 = 4194304:
//   xbf[SZ] | Wbf[SZ] (Wq,Wk,Wv,Wo @ +0/+1M/+2M/+3M) | Qbf[SZ] | Kbf[SZ]
//   | Vt[SZ] ([bh][64][2048]) | Obf[SZ] | qsq[64K f32] ksq[64K f32]
// total ~48.5 MB

using bf16x8 = __attribute__((ext_vector_type(8))) __bf16;
using f32x4  = __attribute__((ext_vector_type(4))) float;

typedef const __attribute__((address_space(1))) void* gas_t;
typedef __attribute__((address_space(3))) void* las_t;

static __device__ __forceinline__ unsigned short f2bf(float x) {
  union { float f; unsigned u; } c; c.f = x;
  unsigned u = c.u;
  u += 0x7fffu + ((u >> 16) & 1u);          // round-to-nearest-even
  return (unsigned short)(u >> 16);
}
static __device__ __forceinline__ float bf2f(unsigned short b) {
  union { unsigned u; float f; } c; c.u = ((unsigned)b) << 16;
  return c.f;
}

// ---------------- f32 -> bf16 convert (vector x4) ----------------
__global__ __launch_bounds__(256)
void cvt_kernel(const float* __restrict__ in, unsigned short* __restrict__ out, int n4) {
  int idx = blockIdx.x * 256 + threadIdx.x;
  if (idx >= n4) return;
  float4 v = ((const float4*)in)[idx];
  ushort4 o;
  o.x = f2bf(v.x); o.y = f2bf(v.y); o.z = f2bf(v.z); o.w = f2bf(v.w);
  ((ushort4*)out)[idx] = o;
}

// ---------------- GEMM: C[M][Ncols] = A[M][K] * Bt[Ncols][K]^T ----------------
// m97 structure: 128x128 tile, 4 waves (2x2), BK=32, global_load_lds width 16.
// mode 0: Ncols=3072 fused QKV. z = gn>>10: z<2 -> bf16 row-major [4096][1024]
//         at out0 + z*SZ; z==2 -> V written TRANSPOSED into Vt[bh][d][n].
// mode 1: f32 row-major [M][1024] (final projection into d_out).
__global__ __launch_bounds__(256)
void gemm_bt(const unsigned short* __restrict__ A,
             const unsigned short* __restrict__ Bt,
             void* __restrict__ out0, int Kdim, int mode) {
  __shared__ unsigned short As[4096];   // [128][32]
  __shared__ unsigned short Bs[4096];   // [128][32]
  const int t  = threadIdx.x;
  const int m0 = blockIdx.x * 128;
  const int n0 = blockIdx.y * 128;
  const int srow = t >> 2;
  const int scol = (t & 3) * 8;
  const unsigned short* pA = A  + (size_t)(m0 + srow) * Kdim + scol;
  const unsigned short* pB = Bt + (size_t)(n0 + srow) * Kdim + scol;
  const size_t rowskip = (size_t)64 * Kdim;

  const int wave = t >> 6, lane = t & 63;
  const int wm = (wave >> 1) * 64, wn = (wave & 1) * 64;
  const int fr = lane & 15, fg = lane >> 4;
  const int aoff = (wm + fr) * 32 + fg * 8;
  const int boff = (wn + fr) * 32 + fg * 8;

  f32x4 acc[4][4];
#pragma unroll
  for (int mi = 0; mi < 4; ++mi)
#pragma unroll
    for (int ni = 0; ni < 4; ++ni)
      acc[mi][ni] = (f32x4){0.f, 0.f, 0.f, 0.f};

  for (int k0 = 0; k0 < Kdim; k0 += 32) {
    __builtin_amdgcn_global_load_lds((gas_t)(const void*)pA,             (las_t)(void*)(As + t * 8),        16, 0, 0);
    __builtin_amdgcn_global_load_lds((gas_t)(const void*)(pA + rowskip), (las_t)(void*)(As + 2048 + t * 8), 16, 0, 0);
    __builtin_amdgcn_global_load_lds((gas_t)(const void*)pB,             (las_t)(void*)(Bs + t * 8),        16, 0, 0);
    __builtin_amdgcn_global_load_lds((gas_t)(const void*)(pB + rowskip), (las_t)(void*)(Bs + 2048 + t * 8), 16, 0, 0);
    pA += 32; pB += 32;
    __syncthreads();

    bf16x8 af[4], bfr[4];
#pragma unroll
    for (int mi = 0; mi < 4; ++mi) af[mi]  = *(const bf16x8*)(As + aoff + mi * 512);
#pragma unroll
    for (int ni = 0; ni < 4; ++ni) bfr[ni] = *(const bf16x8*)(Bs + boff + ni * 512);
#pragma unroll
    for (int mi = 0; mi < 4; ++mi)
#pragma unroll
      for (int ni = 0; ni < 4; ++ni)
        acc[mi][ni] = __builtin_amdgcn_mfma_f32_16x16x32_bf16(af[mi], bfr[ni], acc[mi][ni], 0, 0, 0);
    __syncthreads();
  }

  // epilogue: C/D layout col = lane&15, row = (lane>>4)*4 + r  [m89-verified]
#pragma unroll
  for (int mi = 0; mi < 4; ++mi) {
    const int gm = m0 + wm + mi * 16 + fg * 4;
#pragma unroll
    for (int ni = 0; ni < 4; ++ni) {
      const int gn = n0 + wn + ni * 16 + fr;
      if (mode == 0) {
        unsigned short* outw = (unsigned short*)out0;
        const int z = gn >> 10, col = gn & 1023;
        if (z < 2) {                                   // Q or K, row-major bf16
          unsigned short* dst = outw + (size_t)z * 4194304u;
#pragma unroll
          for (int r = 0; r < 4; ++r)
            dst[(size_t)(gm + r) * 1024 + col] = f2bf(acc[mi][ni][r]);
        } else {                                       // V -> Vt[bh][d][n], 4 consecutive n packed
          ushort4 o4;
          o4.x = f2bf(acc[mi][ni][0]); o4.y = f2bf(acc[mi][ni][1]);
          o4.z = f2bf(acc[mi][ni][2]); o4.w = f2bf(acc[mi][ni][3]);
          const int bb = gm >> 11, nn = gm & 2047;
          const int hh = col >> 6, dd = col & 63;
          unsigned short* vt = outw + (size_t)2 * 4194304u;
          *(ushort4*)(vt + ((size_t)((bb * 16 + hh) * 64 + dd)) * 2048 + nn) = o4;
        }
      } else {                                         // f32 out
        float* dst = (float*)out0;
#pragma unroll
        for (int r = 0; r < 4; ++r)
          dst[(size_t)(gm + r) * 1024 + gn] = acc[mi][ni][r];
      }
    }
  }
}

// ---------------- per-(bh,n) row sum of squares over head dim ----------------
__global__ __launch_bounds__(256)
void rowsq_kernel(const unsigned short* __restrict__ Qbf,
                  const unsigned short* __restrict__ Kbf,
                  float* __restrict__ qsq, float* __restrict__ ksq) {
  const int tid = blockIdx.x * 256 + threadIdx.x;     // 0..65535 = bh*2048 + n
  const unsigned short* src = (blockIdx.y == 0) ? Qbf : Kbf;
  float* dst = (blockIdx.y == 0) ? qsq : ksq;
  const int bh = tid >> 11, n = tid & 2047;
  const int b = bh >> 4, h = bh & 15;
  const unsigned short* row = src + (size_t)(b * 2048 + n) * 1024 + h * 64;
  float s = 0.f;
#pragma unroll
  for (int c = 0; c < 64; c += 4) {
    ushort4 v = *(const ushort4*)(row + c);
    float f0 = bf2f(v.x), f1 = bf2f(v.y), f2 = bf2f(v.z), f3 = bf2f(v.w);
    s += f0 * f0 + f1 * f1 + f2 * f2 + f3 * f3;
  }
  dst[tid] = s;
}

// ---------------- fused RBF attention ----------------
// grid (32 bh, 32 qtiles), 4 waves/block, 16 q-rows per wave.
// Swapped QK^T: S^T = mfma(K, Q) so lane holds col i = q-row; p-values are
// redistributed to PV B-fragments with 8 shuffles (no LDS). No running max
// needed: sim in [0,1] or exp(-1e9)=0.
__global__ __launch_bounds__(256)
void attn_kernel(const unsigned short* __restrict__ Qbf,
                 const unsigned short* __restrict__ Kbf,
                 const unsigned short* __restrict__ Vt,
                 const float* __restrict__ qsq,
                 const float* __restrict__ ksq,
                 const int* __restrict__ mask,
                 unsigned short* __restrict__ Obf) {
  const int bh = blockIdx.x;
  const int b = bh >> 4, h = bh & 15;
  const int wave = threadIdx.x >> 6, lane = threadIdx.x & 63;
  const int q0 = blockIdx.y * 64 + wave * 16;
  const int li = lane & 15, g = lane >> 4;

  const unsigned short* Qrow = Qbf + (size_t)(b * 2048 + q0 + li) * 1024 + h * 64;
  const bf16x8 qlo = *(const bf16x8*)(Qrow + g * 8);
  const bf16x8 qhi = *(const bf16x8*)(Qrow + 32 + g * 8);
  const float qsqi = qsq[bh * 2048 + q0 + li];

  const unsigned short* Kbase = Kbf + (size_t)b * 2048 * 1024 + h * 64;
  const unsigned short* Vbase = Vt + (size_t)bh * 64 * 2048;
  const float* ksqb = ksq + bh * 2048;
  const int* mb = mask + b * 2048;

  f32x4 oacc[4];
#pragma unroll
  for (int dt = 0; dt < 4; ++dt) oacc[dt] = (f32x4){0.f, 0.f, 0.f, 0.f};
  float den = 0.f;

  const int l0 = ((2 * g) & 3) * 16 + li;      // source lanes for P-frag
  const int l1 = ((2 * g + 1) & 3) * 16 + li;

  for (int j0 = 0; j0 < 2048; j0 += 32) {
    const unsigned short* Kr0 = Kbase + (size_t)(j0 + li) * 1024;
    const unsigned short* Kr1 = Kr0 + 16 * 1024;
    bf16x8 kalo = *(const bf16x8*)(Kr0 + g * 8);
    bf16x8 kahi = *(const bf16x8*)(Kr0 + 32 + g * 8);
    bf16x8 kblo = *(const bf16x8*)(Kr1 + g * 8);
    bf16x8 kbhi = *(const bf16x8*)(Kr1 + 32 + g * 8);
    f32x4 stA = (f32x4){0.f, 0.f, 0.f, 0.f};
    f32x4 stB = (f32x4){0.f, 0.f, 0.f, 0.f};
    stA = __builtin_amdgcn_mfma_f32_16x16x32_bf16(kalo, qlo, stA, 0, 0, 0);
    stA = __builtin_amdgcn_mfma_f32_16x16x32_bf16(kahi, qhi, stA, 0, 0, 0);
    stB = __builtin_amdgcn_mfma_f32_16x16x32_bf16(kblo, qlo, stB, 0, 0, 0);
    stB = __builtin_amdgcn_mfma_f32_16x16x32_bf16(kbhi, qhi, stB, 0, 0, 0);
    // stA[r] = S^T[j0+4g+r][q0+li], stB[r] = S^T[j0+16+4g+r][q0+li]

    const float4 kqA = *(const float4*)(ksqb + j0 + 4 * g);
    const float4 kqB = *(const float4*)(ksqb + j0 + 16 + 4 * g);
    const int4  mA4 = *(const int4*)(mb + j0 + 4 * g);
    const int4  mB4 = *(const int4*)(mb + j0 + 16 + 4 * g);
    const float kA[4] = {kqA.x, kqA.y, kqA.z, kqA.w};
    const float kB[4] = {kqB.x, kqB.y, kqB.z, kqB.w};
    const int   mA[4] = {mA4.x, mA4.y, mA4.z, mA4.w};
    const int   mB[4] = {mB4.x, mB4.y, mB4.z, mB4.w};

    float pA[4], pB[4];
#pragma unroll
    for (int r = 0; r < 4; ++r) {
      float dA = fmaxf(qsqi + kA[r] - 2.f * stA[r], 0.f);
      float pa = __expf(__expf(-dA));          // GAMMA = 1
      pa = (mA[r] == 0) ? 0.f : pa;
      float dB = fmaxf(qsqi + kB[r] - 2.f * stB[r], 0.f);
      float pb = __expf(__expf(-dB));
      pb = (mB[r] == 0) ? 0.f : pb;
      pA[r] = pa; pB[r] = pb;
      den += pa + pb;
    }

    unsigned uA0 = (unsigned)f2bf(pA[0]) | ((unsigned)f2bf(pA[1]) << 16);
    unsigned uA1 = (unsigned)f2bf(pA[2]) | ((unsigned)f2bf(pA[3]) << 16);
    unsigned uB0 = (unsigned)f2bf(pB[0]) | ((unsigned)f2bf(pB[1]) << 16);
    unsigned uB1 = (unsigned)f2bf(pB[2]) | ((unsigned)f2bf(pB[3]) << 16);

    unsigned sa0 = __shfl(uA0, l0), sb0 = __shfl(uB0, l0);
    unsigned sa1 = __shfl(uA1, l0), sb1 = __shfl(uB1, l0);
    unsigned sa2 = __shfl(uA0, l1), sb2 = __shfl(uB0, l1);
    unsigned sa3 = __shfl(uA1, l1), sb3 = __shfl(uB1, l1);
    union { unsigned u[4]; bf16x8 v; } pc;
    pc.u[0] = (g < 2) ? sa0 : sb0;
    pc.u[1] = (g < 2) ? sa1 : sb1;
    pc.u[2] = (g < 2) ? sa2 : sb2;
    pc.u[3] = (g < 2) ? sa3 : sb3;
    const bf16x8 pfrag = pc.v;   // B-frag: col=li (q), k = g*8+t (j_local)

#pragma unroll
    for (int dt = 0; dt < 4; ++dt) {
      const bf16x8 vf = *(const bf16x8*)(Vbase + (size_t)(dt * 16 + li) * 2048 + j0 + g * 8);
      oacc[dt] = __builtin_amdgcn_mfma_f32_16x16x32_bf16(vf, pfrag, oacc[dt], 0, 0, 0);
    }
  }

  den += __shfl_xor(den, 16);
  den += __shfl_xor(den, 32);
  const float inv = 1.f / den;

  // oacc[dt][r] = O[q0+li][dt*16 + 4g + r]
  unsigned short* orow = Obf + (size_t)(b * 2048 + q0 + li) * 1024 + h * 64;
#pragma unroll
  for (int dt = 0; dt < 4; ++dt) {
    ushort4 o4;
    o4.x = f2bf(oacc[dt][0] * inv);
    o4.y = f2bf(oacc[dt][1] * inv);
    o4.z = f2bf(oacc[dt][2] * inv);
    o4.w = f2bf(oacc[dt][3] * inv);
    *(ushort4*)(orow + dt * 16 + 4 * g) = o4;
  }
}

extern "C" void kernel_launch(void* const* d_in, const int* in_sizes, int n_in,
                              void* d_out, int out_size, void* d_ws, size_t ws_size,
                              hipStream_t stream) {
  const float* x  = (const float*)d_in[0];
  const float* Wq = (const float*)d_in[1];
  const float* Wk = (const float*)d_in[2];
  const float* Wv = (const float*)d_in[3];
  const float* Wo = (const float*)d_in[4];
  const int* mask = (const int*)d_in[5];

  unsigned short* ws = (unsigned short*)d_ws;
  const size_t SZ = 4194304;                 // 4096*1024
  unsigned short* xbf = ws;
  unsigned short* Wbf = ws + SZ;             // Wq,Wk,Wv,Wo @ +0/+1M/+2M/+3M
  unsigned short* Qbf = ws + 2 * SZ;
  unsigned short* Kbf = ws + 3 * SZ;         // must be Qbf + SZ (gemm mode 0 relies on it)
  unsigned short* Vt  = ws + 4 * SZ;         // [bh][64][2048]
  unsigned short* Obf = ws + 5 * SZ;
  float* qsq = (float*)(ws + 6 * SZ);
  float* ksq = qsq + 65536;

  // 1) f32 -> bf16
  cvt_kernel<<<4096, 256, 0, stream>>>(x,  xbf,            1048576);
  cvt_kernel<<<1024, 256, 0, stream>>>(Wq, Wbf,            262144);
  cvt_kernel<<<1024, 256, 0, stream>>>(Wk, Wbf + 1048576,  262144);
  cvt_kernel<<<1024, 256, 0, stream>>>(Wv, Wbf + 2097152,  262144);
  cvt_kernel<<<1024, 256, 0, stream>>>(Wo, Wbf + 3145728,  262144);

  // 2) fused QKV projection: x @ [Wq;Wk;Wv]^T  (Ncols = 3072)
  gemm_bt<<<dim3(32, 24), 256, 0, stream>>>(xbf, Wbf, Qbf, 1024, 0);

  // 3) q_sq / k_sq
  rowsq_kernel<<<dim3(256, 2), 256, 0, stream>>>(Qbf, Kbf, qsq, ksq);

  // 4) fused RBF attention -> Obf (bf16, [token][e] with e = h*64+d)
  attn_kernel<<<dim3(32, 32), 256, 0, stream>>>(Qbf, Kbf, Vt, qsq, ksq, mask, Obf);

  // 5) output projection: Obf @ Wo^T -> f32 d_out
  gemm_bt<<<dim3(32, 8), 256, 0, stream>>>(Obf, Wbf + 3145728, d_out, 1024, 1);
}

// Round 2
// 198.355 us; speedup vs baseline: 1.7279x; 1.7279x over previous
//
#include <hip/hip_runtime.h>
#include <hip/hip_bf16.h>

// Problem constants: B=2, N=2048, E=1024, H=16, D_K=64, GAMMA=1
//   tokens M = 4096, K = 1024
//
// ws layout (ushort elems), SZ = 4096*1024 = 4194304:
//   xbf[SZ] | Wbf[SZ] (Wq,Wk,Wv,Wo @ +0/+1M/+2M/+3M) | Qbf[SZ] | Kbf[SZ]
//   | Vt[SZ] ([bh][64][2048]) | Obf[SZ] | qsq[64K f32] ksq[64K f32]

using bf16x8 = __attribute__((ext_vector_type(8))) __bf16;
using f32x4  = __attribute__((ext_vector_type(4))) float;

typedef const __attribute__((address_space(1))) void* gas_t;
typedef __attribute__((address_space(3))) void* las_t;

static __device__ __forceinline__ unsigned short f2bf(float x) {
  union { float f; unsigned u; } c; c.f = x;
  unsigned u = c.u;
  u += 0x7fffu + ((u >> 16) & 1u);          // round-to-nearest-even
  return (unsigned short)(u >> 16);
}
static __device__ __forceinline__ float bf2f(unsigned short b) {
  union { unsigned u; float f; } c; c.u = ((unsigned)b) << 16;
  return c.f;
}

// ---------------- f32 -> bf16 convert (vector x4) ----------------
__global__ __launch_bounds__(256)
void cvt_kernel(const float* __restrict__ in, unsigned short* __restrict__ out, int n4) {
  int idx = blockIdx.x * 256 + threadIdx.x;
  if (idx >= n4) return;
  float4 v = ((const float4*)in)[idx];
  ushort4 o;
  o.x = f2bf(v.x); o.y = f2bf(v.y); o.z = f2bf(v.z); o.w = f2bf(v.w);
  ((ushort4*)out)[idx] = o;
}

// ---------------- GEMM: C[M][Ncols] = A[M][K] * Bt[Ncols][K]^T ----------------
// m97 structure: 128x128 tile, 4 waves (2x2), BK=32, global_load_lds width 16.
__global__ __launch_bounds__(256)
void gemm_bt(const unsigned short* __restrict__ A,
             const unsigned short* __restrict__ Bt,
             void* __restrict__ out0, int Kdim, int mode) {
  __shared__ unsigned short As[4096];   // [128][32]
  __shared__ unsigned short Bs[4096];   // [128][32]
  const int t  = threadIdx.x;
  const int m0 = blockIdx.x * 128;
  const int n0 = blockIdx.y * 128;
  const int srow = t >> 2;
  const int scol = (t & 3) * 8;
  const unsigned short* pA = A  + (size_t)(m0 + srow) * Kdim + scol;
  const unsigned short* pB = Bt + (size_t)(n0 + srow) * Kdim + scol;
  const size_t rowskip = (size_t)64 * Kdim;

  const int wave = t >> 6, lane = t & 63;
  const int wm = (wave >> 1) * 64, wn = (wave & 1) * 64;
  const int fr = lane & 15, fg = lane >> 4;
  const int aoff = (wm + fr) * 32 + fg * 8;
  const int boff = (wn + fr) * 32 + fg * 8;

  f32x4 acc[4][4];
#pragma unroll
  for (int mi = 0; mi < 4; ++mi)
#pragma unroll
    for (int ni = 0; ni < 4; ++ni)
      acc[mi][ni] = (f32x4){0.f, 0.f, 0.f, 0.f};

  for (int k0 = 0; k0 < Kdim; k0 += 32) {
    __builtin_amdgcn_global_load_lds((gas_t)(const void*)pA,             (las_t)(void*)(As + t * 8),        16, 0, 0);
    __builtin_amdgcn_global_load_lds((gas_t)(const void*)(pA + rowskip), (las_t)(void*)(As + 2048 + t * 8), 16, 0, 0);
    __builtin_amdgcn_global_load_lds((gas_t)(const void*)pB,             (las_t)(void*)(Bs + t * 8),        16, 0, 0);
    __builtin_amdgcn_global_load_lds((gas_t)(const void*)(pB + rowskip), (las_t)(void*)(Bs + 2048 + t * 8), 16, 0, 0);
    pA += 32; pB += 32;
    __syncthreads();

    bf16x8 af[4], bfr[4];
#pragma unroll
    for (int mi = 0; mi < 4; ++mi) af[mi]  = *(const bf16x8*)(As + aoff + mi * 512);
#pragma unroll
    for (int ni = 0; ni < 4; ++ni) bfr[ni] = *(const bf16x8*)(Bs + boff + ni * 512);
#pragma unroll
    for (int mi = 0; mi < 4; ++mi)
#pragma unroll
      for (int ni = 0; ni < 4; ++ni)
        acc[mi][ni] = __builtin_amdgcn_mfma_f32_16x16x32_bf16(af[mi], bfr[ni], acc[mi][ni], 0, 0, 0);
    __syncthreads();
  }

  // epilogue: C/D layout col = lane&15, row = (lane>>4)*4 + r  [m89-verified]
#pragma unroll
  for (int mi = 0; mi < 4; ++mi) {
    const int gm = m0 + wm + mi * 16 + fg * 4;
#pragma unroll
    for (int ni = 0; ni < 4; ++ni) {
      const int gn = n0 + wn + ni * 16 + fr;
      if (mode == 0) {
        unsigned short* outw = (unsigned short*)out0;
        const int z = gn >> 10, col = gn & 1023;
        if (z < 2) {                                   // Q or K, row-major bf16
          unsigned short* dst = outw + (size_t)z * 4194304u;
#pragma unroll
          for (int r = 0; r < 4; ++r)
            dst[(size_t)(gm + r) * 1024 + col] = f2bf(acc[mi][ni][r]);
        } else {                                       // V -> Vt[bh][d][n]
          ushort4 o4;
          o4.x = f2bf(acc[mi][ni][0]); o4.y = f2bf(acc[mi][ni][1]);
          o4.z = f2bf(acc[mi][ni][2]); o4.w = f2bf(acc[mi][ni][3]);
          const int bb = gm >> 11, nn = gm & 2047;
          const int hh = col >> 6, dd = col & 63;
          unsigned short* vt = outw + (size_t)2 * 4194304u;
          *(ushort4*)(vt + ((size_t)((bb * 16 + hh) * 64 + dd)) * 2048 + nn) = o4;
        }
      } else {                                         // f32 out
        float* dst = (float*)out0;
#pragma unroll
        for (int r = 0; r < 4; ++r)
          dst[(size_t)(gm + r) * 1024 + gn] = acc[mi][ni][r];
      }
    }
  }
}

// ---------------- per-(bh,n) row sum of squares over head dim ----------------
__global__ __launch_bounds__(256)
void rowsq_kernel(const unsigned short* __restrict__ Qbf,
                  const unsigned short* __restrict__ Kbf,
                  float* __restrict__ qsq, float* __restrict__ ksq) {
  const int tid = blockIdx.x * 256 + threadIdx.x;     // 0..65535 = bh*2048 + n
  const unsigned short* src = (blockIdx.y == 0) ? Qbf : Kbf;
  float* dst = (blockIdx.y == 0) ? qsq : ksq;
  const int bh = tid >> 11, n = tid & 2047;
  const int b = bh >> 4, h = bh & 15;
  const unsigned short* row = src + (size_t)(b * 2048 + n) * 1024 + h * 64;
  float s = 0.f;
#pragma unroll
  for (int c = 0; c < 64; c += 4) {
    ushort4 v = *(const ushort4*)(row + c);
    float f0 = bf2f(v.x), f1 = bf2f(v.y), f2 = bf2f(v.z), f3 = bf2f(v.w);
    s += f0 * f0 + f1 * f1 + f2 * f2 + f3 * f3;
  }
  dst[tid] = s;
}

// ---------------- fused RBF attention (LDS-staged, double-buffered) ----------------
// grid (32 bh, 32 qtiles), 4 waves/block, 16 q-rows per wave, KVBLK=64.
// K tile [64][64] and Vt tile [64 d][64 n] staged in LDS via global_load_lds,
// shared by all 4 waves. 128B rows -> pre-swizzled source (chunk ^= row&7) so
// ds_read_b128 spreads 16-lane groups over all 8 bank-groups (rule #21:
// linear LDS dest + inverse-swizzled global src + swizzle on read).
// 2-phase pipeline: stage(next) issued BEFORE compute(cur); one barrier/tile.
__global__ __launch_bounds__(256)
void attn_kernel(const unsigned short* __restrict__ Qbf,
                 const unsigned short* __restrict__ Kbf,
                 const unsigned short* __restrict__ Vt,
                 const float* __restrict__ qsq,
                 const float* __restrict__ ksq,
                 const int* __restrict__ mask,
                 unsigned short* __restrict__ Obf) {
  __shared__ unsigned short Ks[2][4096];   // [buf][64 rows][64 cols] swizzled
  __shared__ unsigned short Vs[2][4096];   // [buf][64 d][64 n] swizzled

  const int bh = blockIdx.x;
  const int b = bh >> 4, h = bh & 15;
  const int t = threadIdx.x;
  const int wave = t >> 6, lane = t & 63;
  const int q0 = blockIdx.y * 64 + wave * 16;
  const int li = lane & 15, g = lane >> 4;
  const int sw = li & 7;

  const unsigned short* Qrow = Qbf + (size_t)(b * 2048 + q0 + li) * 1024 + h * 64;
  const bf16x8 qlo = *(const bf16x8*)(Qrow + g * 8);
  const bf16x8 qhi = *(const bf16x8*)(Qrow + 32 + g * 8);
  const float qsqi = qsq[bh * 2048 + q0 + li];

  const unsigned short* Kbase = Kbf + (size_t)b * 2048 * 1024 + h * 64;
  const unsigned short* VtB = Vt + (size_t)bh * 64 * 2048;
  const float* ksqb = ksq + bh * 2048;
  const int* mb = mask + b * 2048;

  // staging: chunk p (16B) of an 8KB tile; row = p>>3, store pos cp = p&7
  // holds logical chunk cl = cp ^ (row&7).
  const int p0 = t,        r0 = p0 >> 3, c0 = (p0 & 7) ^ (r0 & 7);
  const int p1 = 256 + t,  r1 = p1 >> 3, c1 = (p1 & 7) ^ (r1 & 7);

  f32x4 oacc[4];
#pragma unroll
  for (int dt = 0; dt < 4; ++dt) oacc[dt] = (f32x4){0.f, 0.f, 0.f, 0.f};
  float den = 0.f;

  const int l0 = ((2 * g) & 3) * 16 + li;      // source lanes for P-frag
  const int l1 = ((2 * g + 1) & 3) * 16 + li;

#define STAGE(bi, tj)                                                                               \
  do {                                                                                              \
    const int j0s = (tj) * 64;                                                                      \
    __builtin_amdgcn_global_load_lds((gas_t)(const void*)(Kbase + (size_t)(j0s + r0) * 1024 + c0 * 8), \
                                     (las_t)(void*)(Ks[bi] + p0 * 8), 16, 0, 0);                    \
    __builtin_amdgcn_global_load_lds((gas_t)(const void*)(Kbase + (size_t)(j0s + r1) * 1024 + c1 * 8), \
                                     (las_t)(void*)(Ks[bi] + p1 * 8), 16, 0, 0);                    \
    __builtin_amdgcn_global_load_lds((gas_t)(const void*)(VtB + (size_t)r0 * 2048 + j0s + c0 * 8),  \
                                     (las_t)(void*)(Vs[bi] + p0 * 8), 16, 0, 0);                    \
    __builtin_amdgcn_global_load_lds((gas_t)(const void*)(VtB + (size_t)r1 * 2048 + j0s + c1 * 8),  \
                                     (las_t)(void*)(Vs[bi] + p1 * 8), 16, 0, 0);                    \
  } while (0)

  STAGE(0, 0);
  __syncthreads();

  for (int tj = 0; tj < 32; ++tj) {
    const int cur = tj & 1;
    if (tj + 1 < 32) STAGE(cur ^ 1, tj + 1);

    const unsigned short* Kc = Ks[cur];
    const unsigned short* Vc = Vs[cur];
    const int j0 = tj * 64;

#pragma unroll
    for (int jj = 0; jj < 64; jj += 32) {
      const bf16x8 kalo = *(const bf16x8*)(Kc + (jj + li) * 64      + (g ^ sw) * 8);
      const bf16x8 kahi = *(const bf16x8*)(Kc + (jj + li) * 64      + ((g + 4) ^ sw) * 8);
      const bf16x8 kblo = *(const bf16x8*)(Kc + (jj + 16 + li) * 64 + (g ^ sw) * 8);
      const bf16x8 kbhi = *(const bf16x8*)(Kc + (jj + 16 + li) * 64 + ((g + 4) ^ sw) * 8);
      f32x4 stA = (f32x4){0.f, 0.f, 0.f, 0.f};
      f32x4 stB = (f32x4){0.f, 0.f, 0.f, 0.f};
      stA = __builtin_amdgcn_mfma_f32_16x16x32_bf16(kalo, qlo, stA, 0, 0, 0);
      stA = __builtin_amdgcn_mfma_f32_16x16x32_bf16(kahi, qhi, stA, 0, 0, 0);
      stB = __builtin_amdgcn_mfma_f32_16x16x32_bf16(kblo, qlo, stB, 0, 0, 0);
      stB = __builtin_amdgcn_mfma_f32_16x16x32_bf16(kbhi, qhi, stB, 0, 0, 0);
      // stA[r] = S^T[j0+jj+4g+r][q0+li], stB[r] = S^T[j0+jj+16+4g+r][q0+li]

      const int j0j = j0 + jj;
      const float4 kqA = *(const float4*)(ksqb + j0j + 4 * g);
      const float4 kqB = *(const float4*)(ksqb + j0j + 16 + 4 * g);
      const int4  mA4 = *(const int4*)(mb + j0j + 4 * g);
      const int4  mB4 = *(const int4*)(mb + j0j + 16 + 4 * g);
      const float kA[4] = {kqA.x, kqA.y, kqA.z, kqA.w};
      const float kB[4] = {kqB.x, kqB.y, kqB.z, kqB.w};
      const int   mA[4] = {mA4.x, mA4.y, mA4.z, mA4.w};
      const int   mB[4] = {mB4.x, mB4.y, mB4.z, mB4.w};

      float pA[4], pB[4];
#pragma unroll
      for (int r = 0; r < 4; ++r) {
        float dA = fmaxf(qsqi + kA[r] - 2.f * stA[r], 0.f);
        float pa = __expf(__expf(-dA));          // GAMMA = 1; sim in [0,1] -> no max needed
        pa = (mA[r] == 0) ? 0.f : pa;
        float dB = fmaxf(qsqi + kB[r] - 2.f * stB[r], 0.f);
        float pb = __expf(__expf(-dB));
        pb = (mB[r] == 0) ? 0.f : pb;
        pA[r] = pa; pB[r] = pb;
        den += pa + pb;
      }

      unsigned uA0 = (unsigned)f2bf(pA[0]) | ((unsigned)f2bf(pA[1]) << 16);
      unsigned uA1 = (unsigned)f2bf(pA[2]) | ((unsigned)f2bf(pA[3]) << 16);
      unsigned uB0 = (unsigned)f2bf(pB[0]) | ((unsigned)f2bf(pB[1]) << 16);
      unsigned uB1 = (unsigned)f2bf(pB[2]) | ((unsigned)f2bf(pB[3]) << 16);

      unsigned sa0 = __shfl(uA0, l0), sb0 = __shfl(uB0, l0);
      unsigned sa1 = __shfl(uA1, l0), sb1 = __shfl(uB1, l0);
      unsigned sa2 = __shfl(uA0, l1), sb2 = __shfl(uB0, l1);
      unsigned sa3 = __shfl(uA1, l1), sb3 = __shfl(uB1, l1);
      union { unsigned u[4]; bf16x8 v; } pc;
      pc.u[0] = (g < 2) ? sa0 : sb0;
      pc.u[1] = (g < 2) ? sa1 : sb1;
      pc.u[2] = (g < 2) ? sa2 : sb2;
      pc.u[3] = (g < 2) ? sa3 : sb3;
      const bf16x8 pfrag = pc.v;   // B-frag: col=li (q), k = g*8+t (j_local)

#pragma unroll
      for (int dt = 0; dt < 4; ++dt) {
        const bf16x8 vf = *(const bf16x8*)(Vc + (dt * 16 + li) * 64 + (((jj >> 3) + g) ^ sw) * 8);
        oacc[dt] = __builtin_amdgcn_mfma_f32_16x16x32_bf16(vf, pfrag, oacc[dt], 0, 0, 0);
      }
    }
    __syncthreads();   // drains next-tile stage loads (they flew under compute)
  }
#undef STAGE

  den += __shfl_xor(den, 16);
  den += __shfl_xor(den, 32);
  const float inv = 1.f / den;

  // oacc[dt][r] = O[q0+li][dt*16 + 4g + r]
  unsigned short* orow = Obf + (size_t)(b * 2048 + q0 + li) * 1024 + h * 64;
#pragma unroll
  for (int dt = 0; dt < 4; ++dt) {
    ushort4 o4;
    o4.x = f2bf(oacc[dt][0] * inv);
    o4.y = f2bf(oacc[dt][1] * inv);
    o4.z = f2bf(oacc[dt][2] * inv);
    o4.w = f2bf(oacc[dt][3] * inv);
    *(ushort4*)(orow + dt * 16 + 4 * g) = o4;
  }
}

extern "C" void kernel_launch(void* const* d_in, const int* in_sizes, int n_in,
                              void* d_out, int out_size, void* d_ws, size_t ws_size,
                              hipStream_t stream) {
  const float* x  = (const float*)d_in[0];
  const float* Wq = (const float*)d_in[1];
  const float* Wk = (const float*)d_in[2];
  const float* Wv = (const float*)d_in[3];
  const float* Wo = (const float*)d_in[4];
  const int* mask = (const int*)d_in[5];

  unsigned short* ws = (unsigned short*)d_ws;
  const size_t SZ = 4194304;                 // 4096*1024
  unsigned short* xbf = ws;
  unsigned short* Wbf = ws + SZ;             // Wq,Wk,Wv,Wo @ +0/+1M/+2M/+3M
  unsigned short* Qbf = ws + 2 * SZ;
  unsigned short* Kbf = ws + 3 * SZ;         // must be Qbf + SZ (gemm mode 0 relies on it)
  unsigned short* Vt  = ws + 4 * SZ;         // [bh][64][2048]
  unsigned short* Obf = ws + 5 * SZ;
  float* qsq = (float*)(ws + 6 * SZ);
  float* ksq = qsq + 65536;

  // 1) f32 -> bf16
  cvt_kernel<<<4096, 256, 0, stream>>>(x,  xbf,            1048576);
  cvt_kernel<<<1024, 256, 0, stream>>>(Wq, Wbf,            262144);
  cvt_kernel<<<1024, 256, 0, stream>>>(Wk, Wbf + 1048576,  262144);
  cvt_kernel<<<1024, 256, 0, stream>>>(Wv, Wbf + 2097152,  262144);
  cvt_kernel<<<1024, 256, 0, stream>>>(Wo, Wbf + 3145728,  262144);

  // 2) fused QKV projection: x @ [Wq;Wk;Wv]^T  (Ncols = 3072)
  gemm_bt<<<dim3(32, 24), 256, 0, stream>>>(xbf, Wbf, Qbf, 1024, 0);

  // 3) q_sq / k_sq
  rowsq_kernel<<<dim3(256, 2), 256, 0, stream>>>(Qbf, Kbf, qsq, ksq);

  // 4) fused RBF attention -> Obf (bf16, [token][e] with e = h*64+d)
  attn_kernel<<<dim3(32, 32), 256, 0, stream>>>(Qbf, Kbf, Vt, qsq, ksq, mask, Obf);

  // 5) output projection: Obf @ Wo^T -> f32 d_out
  gemm_bt<<<dim3(32, 8), 256, 0, stream>>>(Obf, Wbf + 3145728, d_out, 1024, 1);
}

// Round 3
// 190.043 us; speedup vs baseline: 1.8035x; 1.0437x over previous
//
#include <hip/hip_runtime.h>
#include <hip/hip_bf16.h>

// Problem constants: B=2, N=2048, E=1024, H=16, D_K=64, GAMMA=1
//   tokens M = 4096, K = 1024
//
// ws layout (ushort elems), SZ = 4096*1024 = 4194304:
//   xbf[SZ] | Wbf[SZ] (Wq,Wk,Wv,Wo @ +0/+1M/+2M/+3M) | Qbf[SZ] | Kbf[SZ]
//   | Vt[SZ] ([bh][64][2048]) | Obf[SZ] | qsqp[64K f32] ksqp[64K f32] maskf[4K f32]
//
// Numerics: Qbf holds 2c*q (c = log2 e). qsqp = -c*|q|^2, ksqp = -c*|k|^2.
// QK MFMA with C-init = qsqp+ksqp gives z = -c*d directly; inner = 2^min(z,0)
// = exp(-d); p = 2^(c*inner - c) = exp(sim - 1) (softmax shift-invariant);
// masked -> p *= 0.

using bf16x8 = __attribute__((ext_vector_type(8))) __bf16;
using f32x4  = __attribute__((ext_vector_type(4))) float;
using f32x16 = __attribute__((ext_vector_type(16))) float;

typedef const __attribute__((address_space(1))) void* gas_t;
typedef __attribute__((address_space(3))) void* las_t;

#define C_LOG2E 1.4426950408889634f
#define TWO_C   2.8853900817779268f
#define NEG_INV_4C (-0.17328679513998632f)

#if __has_builtin(__builtin_amdgcn_exp2f)
#define EXP2(x) __builtin_amdgcn_exp2f(x)
#else
#define EXP2(x) __expf((x) * 0.6931471805599453f)
#endif

static __device__ __forceinline__ unsigned short f2bf(float x) {
  union { float f; unsigned u; } c; c.f = x;
  unsigned u = c.u;
  u += 0x7fffu + ((u >> 16) & 1u);          // round-to-nearest-even
  return (unsigned short)(u >> 16);
}
static __device__ __forceinline__ float bf2f(unsigned short b) {
  union { unsigned u; float f; } c; c.u = ((unsigned)b) << 16;
  return c.f;
}
static __device__ __forceinline__ unsigned cvt_pk_bf16(float lo, float hi) {
  unsigned r;
  asm("v_cvt_pk_bf16_f32 %0, %1, %2" : "=v"(r) : "v"(lo), "v"(hi));
  return r;
}
static __device__ __forceinline__ void permlane32_swap(unsigned &a, unsigned &b) {
#if __has_builtin(__builtin_amdgcn_permlane32_swap)
  auto r = __builtin_amdgcn_permlane32_swap(a, b, false, false);
  a = r[0]; b = r[1];
#else
  asm("v_permlane32_swap_b32 %0, %1" : "+v"(a), "+v"(b));
#endif
}

// ---------------- f32 -> bf16 convert (vector x4) ----------------
__global__ __launch_bounds__(256)
void cvt_kernel(const float* __restrict__ in, unsigned short* __restrict__ out, int n4) {
  int idx = blockIdx.x * 256 + threadIdx.x;
  if (idx >= n4) return;
  float4 v = ((const float4*)in)[idx];
  ushort4 o;
  o.x = f2bf(v.x); o.y = f2bf(v.y); o.z = f2bf(v.z); o.w = f2bf(v.w);
  ((ushort4*)out)[idx] = o;
}

// ---------------- GEMM: C[M][Ncols] = A[M][K] * Bt[Ncols][K]^T ----------------
// m97 structure: 128x128 tile, 4 waves (2x2), BK=32, global_load_lds width 16.
// mode 0: Q (scaled by 2c) / K row-major bf16; V -> Vt[bh][d][n]. mode 1: f32 out.
__global__ __launch_bounds__(256)
void gemm_bt(const unsigned short* __restrict__ A,
             const unsigned short* __restrict__ Bt,
             void* __restrict__ out0, int Kdim, int mode) {
  __shared__ unsigned short As[4096];   // [128][32]
  __shared__ unsigned short Bs[4096];   // [128][32]
  const int t  = threadIdx.x;
  const int m0 = blockIdx.x * 128;
  const int n0 = blockIdx.y * 128;
  const int srow = t >> 2;
  const int scol = (t & 3) * 8;
  const unsigned short* pA = A  + (size_t)(m0 + srow) * Kdim + scol;
  const unsigned short* pB = Bt + (size_t)(n0 + srow) * Kdim + scol;
  const size_t rowskip = (size_t)64 * Kdim;

  const int wave = t >> 6, lane = t & 63;
  const int wm = (wave >> 1) * 64, wn = (wave & 1) * 64;
  const int fr = lane & 15, fg = lane >> 4;
  const int aoff = (wm + fr) * 32 + fg * 8;
  const int boff = (wn + fr) * 32 + fg * 8;

  f32x4 acc[4][4];
#pragma unroll
  for (int mi = 0; mi < 4; ++mi)
#pragma unroll
    for (int ni = 0; ni < 4; ++ni)
      acc[mi][ni] = (f32x4){0.f, 0.f, 0.f, 0.f};

  for (int k0 = 0; k0 < Kdim; k0 += 32) {
    __builtin_amdgcn_global_load_lds((gas_t)(const void*)pA,             (las_t)(void*)(As + t * 8),        16, 0, 0);
    __builtin_amdgcn_global_load_lds((gas_t)(const void*)(pA + rowskip), (las_t)(void*)(As + 2048 + t * 8), 16, 0, 0);
    __builtin_amdgcn_global_load_lds((gas_t)(const void*)pB,             (las_t)(void*)(Bs + t * 8),        16, 0, 0);
    __builtin_amdgcn_global_load_lds((gas_t)(const void*)(pB + rowskip), (las_t)(void*)(Bs + 2048 + t * 8), 16, 0, 0);
    pA += 32; pB += 32;
    __syncthreads();

    bf16x8 af[4], bfr[4];
#pragma unroll
    for (int mi = 0; mi < 4; ++mi) af[mi]  = *(const bf16x8*)(As + aoff + mi * 512);
#pragma unroll
    for (int ni = 0; ni < 4; ++ni) bfr[ni] = *(const bf16x8*)(Bs + boff + ni * 512);
#pragma unroll
    for (int mi = 0; mi < 4; ++mi)
#pragma unroll
      for (int ni = 0; ni < 4; ++ni)
        acc[mi][ni] = __builtin_amdgcn_mfma_f32_16x16x32_bf16(af[mi], bfr[ni], acc[mi][ni], 0, 0, 0);
    __syncthreads();
  }

  // epilogue: C/D layout col = lane&15, row = (lane>>4)*4 + r  [m89-verified]
#pragma unroll
  for (int mi = 0; mi < 4; ++mi) {
    const int gm = m0 + wm + mi * 16 + fg * 4;
#pragma unroll
    for (int ni = 0; ni < 4; ++ni) {
      const int gn = n0 + wn + ni * 16 + fr;
      if (mode == 0) {
        unsigned short* outw = (unsigned short*)out0;
        const int z = gn >> 10, col = gn & 1023;
        if (z < 2) {                                   // Q (scaled) or K, row-major bf16
          const float sc = (z == 0) ? TWO_C : 1.0f;
          unsigned short* dst = outw + (size_t)z * 4194304u;
#pragma unroll
          for (int r = 0; r < 4; ++r)
            dst[(size_t)(gm + r) * 1024 + col] = f2bf(acc[mi][ni][r] * sc);
        } else {                                       // V -> Vt[bh][d][n]
          ushort4 o4;
          o4.x = f2bf(acc[mi][ni][0]); o4.y = f2bf(acc[mi][ni][1]);
          o4.z = f2bf(acc[mi][ni][2]); o4.w = f2bf(acc[mi][ni][3]);
          const int bb = gm >> 11, nn = gm & 2047;
          const int hh = col >> 6, dd = col & 63;
          unsigned short* vt = outw + (size_t)2 * 4194304u;
          *(ushort4*)(vt + ((size_t)((bb * 16 + hh) * 64 + dd)) * 2048 + nn) = o4;
        }
      } else {                                         // f32 out
        float* dst = (float*)out0;
#pragma unroll
        for (int r = 0; r < 4; ++r)
          dst[(size_t)(gm + r) * 1024 + gn] = acc[mi][ni][r];
      }
    }
  }
}

// ---------------- per-(bh,n) scaled row sumsq + mask->float ----------------
__global__ __launch_bounds__(256)
void rowsq_kernel(const unsigned short* __restrict__ Qbf,
                  const unsigned short* __restrict__ Kbf,
                  const int* __restrict__ mask,
                  float* __restrict__ qsqp, float* __restrict__ ksqp,
                  float* __restrict__ maskf) {
  const int tid = blockIdx.x * 256 + threadIdx.x;     // 0..65535 = bh*2048 + n
  const int kpath = blockIdx.y;
  const unsigned short* src = (kpath == 0) ? Qbf : Kbf;
  const int bh = tid >> 11, n = tid & 2047;
  const int b = bh >> 4, h = bh & 15;
  const unsigned short* row = src + (size_t)(b * 2048 + n) * 1024 + h * 64;
  float s = 0.f;
#pragma unroll
  for (int c = 0; c < 64; c += 4) {
    ushort4 v = *(const ushort4*)(row + c);
    float f0 = bf2f(v.x), f1 = bf2f(v.y), f2 = bf2f(v.z), f3 = bf2f(v.w);
    s += f0 * f0 + f1 * f1 + f2 * f2 + f3 * f3;
  }
  if (kpath == 0) {
    qsqp[tid] = s * NEG_INV_4C;      // Q was prescaled by 2c: -c*|q|^2 = -s/(4c)
  } else {
    ksqp[tid] = s * (-C_LOG2E);
    if (tid < 4096) maskf[tid] = (mask[tid] == 0) ? 0.f : 1.f;
  }
}

// ---------------- fused RBF attention, 32x32x16 MFMA + permlane P-redistribution ----
// grid (32 bh, 32 qtiles), 4 waves: wave = qg*2 + hf; qg in {0,1} picks 32 q-rows,
// hf splits the 64-k tile. Wave pairs combine O/den via LDS at the end.
__global__ __launch_bounds__(256)
void attn_kernel(const unsigned short* __restrict__ Qbf,
                 const unsigned short* __restrict__ Kbf,
                 const unsigned short* __restrict__ Vt,
                 const float* __restrict__ qsqp,
                 const float* __restrict__ ksqp,
                 const float* __restrict__ maskf,
                 unsigned short* __restrict__ Obf) {
  __shared__ unsigned short Ks[2][4096];   // [buf][64 k][64 d] swizzled (chunk^=row&7)
  __shared__ unsigned short Vs[2][4096];   // [buf][64 d][64 n] swizzled

  const int bh = blockIdx.x;
  const int b = bh >> 4, h = bh & 15;
  const int t = threadIdx.x;
  const int wave = t >> 6, lane = t & 63;
  const int qg = wave >> 1, hf = wave & 1;
  const int li = lane & 31, hi = lane >> 5;
  const int q0 = blockIdx.y * 64 + qg * 32;
  const int qrow = q0 + li;

  // Q fragments: B-operand, lane holds Q[qrow][dblk*16 + hi*8 + e]
  const unsigned short* Qr = Qbf + (size_t)(b * 2048 + qrow) * 1024 + h * 64 + hi * 8;
  bf16x8 qf[4];
#pragma unroll
  for (int dblk = 0; dblk < 4; ++dblk) qf[dblk] = *(const bf16x8*)(Qr + dblk * 16);

  const float qsl = qsqp[bh * 2048 + qrow];
  const float* ksb = ksqp + bh * 2048 + 4 * hi;
  const float* mfb = maskf + b * 2048 + 4 * hi;

  const unsigned short* Kbase = Kbf + (size_t)b * 2048 * 1024 + h * 64;
  const unsigned short* VtB = Vt + (size_t)bh * 64 * 2048;

  // staging: chunk p (16B) of an 8KB tile; row = p>>3, slot cp = p&7 holds
  // logical chunk cl = cp ^ (row&7)  (read side XORs the same way).
  const int p0 = t,        r0 = p0 >> 3, c0 = (p0 & 7) ^ (r0 & 7);
  const int p1 = 256 + t,  r1 = p1 >> 3, c1 = (p1 & 7) ^ (r1 & 7);

  f32x16 oa0, oa1;
#pragma unroll
  for (int r = 0; r < 16; ++r) { oa0[r] = 0.f; oa1[r] = 0.f; }
  float den = 0.f;

#define STAGE(bi, tj)                                                                               \
  do {                                                                                              \
    const int j0s = (tj) * 64;                                                                      \
    __builtin_amdgcn_global_load_lds((gas_t)(const void*)(Kbase + (size_t)(j0s + r0) * 1024 + c0 * 8), \
                                     (las_t)(void*)(Ks[bi] + p0 * 8), 16, 0, 0);                    \
    __builtin_amdgcn_global_load_lds((gas_t)(const void*)(Kbase + (size_t)(j0s + r1) * 1024 + c1 * 8), \
                                     (las_t)(void*)(Ks[bi] + p1 * 8), 16, 0, 0);                    \
    __builtin_amdgcn_global_load_lds((gas_t)(const void*)(VtB + (size_t)r0 * 2048 + j0s + c0 * 8),  \
                                     (las_t)(void*)(Vs[bi] + p0 * 8), 16, 0, 0);                    \
    __builtin_amdgcn_global_load_lds((gas_t)(const void*)(VtB + (size_t)r1 * 2048 + j0s + c1 * 8),  \
                                     (las_t)(void*)(Vs[bi] + p1 * 8), 16, 0, 0);                    \
  } while (0)

  STAGE(0, 0);
  __syncthreads();

  const int jw = hf * 32;            // this wave's k-offset within the 64-k tile
  const int krow = jw + li;          // K LDS row
  const int ksw = krow & 7;

  for (int tj = 0; tj < 32; ++tj) {
    const int cur = tj & 1;
    if (tj + 1 < 32) STAGE(cur ^ 1, tj + 1);

    const unsigned short* Kc = Ks[cur];
    const unsigned short* Vc = Vs[cur];
    const int j0 = tj * 64 + jw;     // global k base for this wave

    // C-init: st[r] = qsq' + ksq'[k], k = (r&3) + 8*(r>>2) + 4*hi
    const float4 kq0 = *(const float4*)(ksb + j0);
    const float4 kq1 = *(const float4*)(ksb + j0 + 8);
    const float4 kq2 = *(const float4*)(ksb + j0 + 16);
    const float4 kq3 = *(const float4*)(ksb + j0 + 24);
    f32x16 st;
    st[0]  = kq0.x + qsl; st[1]  = kq0.y + qsl; st[2]  = kq0.z + qsl; st[3]  = kq0.w + qsl;
    st[4]  = kq1.x + qsl; st[5]  = kq1.y + qsl; st[6]  = kq1.z + qsl; st[7]  = kq1.w + qsl;
    st[8]  = kq2.x + qsl; st[9]  = kq2.y + qsl; st[10] = kq2.z + qsl; st[11] = kq2.w + qsl;
    st[12] = kq3.x + qsl; st[13] = kq3.y + qsl; st[14] = kq3.z + qsl; st[15] = kq3.w + qsl;

    // QK^T: st += K_tile * Q^T  (A = K rows, B = Q cols)
    const unsigned short* Krow = Kc + krow * 64;
    __builtin_amdgcn_s_setprio(1);
#pragma unroll
    for (int dblk = 0; dblk < 4; ++dblk) {
      const bf16x8 kf = *(const bf16x8*)(Krow + ((dblk * 2 + hi) ^ ksw) * 8);
      st = __builtin_amdgcn_mfma_f32_32x32x16_bf16(kf, qf[dblk], st, 0, 0, 0);
    }
    __builtin_amdgcn_s_setprio(0);

    // scores: z = min(st,0); inner = 2^z; p = 2^(c*inner - c) * mask
    const float4 mf0 = *(const float4*)(mfb + j0);
    const float4 mf1 = *(const float4*)(mfb + j0 + 8);
    const float4 mf2 = *(const float4*)(mfb + j0 + 16);
    const float4 mf3 = *(const float4*)(mfb + j0 + 24);
    const float mfa[16] = {mf0.x, mf0.y, mf0.z, mf0.w, mf1.x, mf1.y, mf1.z, mf1.w,
                           mf2.x, mf2.y, mf2.z, mf2.w, mf3.x, mf3.y, mf3.z, mf3.w};
    float pv[16];
#pragma unroll
    for (int r = 0; r < 16; ++r) {
      const float z  = __builtin_fminf(st[r], 0.f);
      const float in = EXP2(z);
      const float pe = EXP2(__builtin_fmaf(C_LOG2E, in, -C_LOG2E));
      const float p  = pe * mfa[r];
      pv[r] = p;
      den += p;
    }

    // P redistribution: cvt_pk pairs, permlane32_swap -> B-fragments
    unsigned u00 = cvt_pk_bf16(pv[0],  pv[1]);
    unsigned u01 = cvt_pk_bf16(pv[2],  pv[3]);
    unsigned u10 = cvt_pk_bf16(pv[4],  pv[5]);
    unsigned u11 = cvt_pk_bf16(pv[6],  pv[7]);
    unsigned u20 = cvt_pk_bf16(pv[8],  pv[9]);
    unsigned u21 = cvt_pk_bf16(pv[10], pv[11]);
    unsigned u30 = cvt_pk_bf16(pv[12], pv[13]);
    unsigned u31 = cvt_pk_bf16(pv[14], pv[15]);
    permlane32_swap(u00, u10);   // -> pf0 words 0,2
    permlane32_swap(u01, u11);   // -> pf0 words 1,3
    permlane32_swap(u20, u30);   // -> pf1 words 0,2
    permlane32_swap(u21, u31);   // -> pf1 words 1,3
    union { unsigned u[4]; bf16x8 v; } pf0, pf1;
    pf0.u[0] = u00; pf0.u[1] = u01; pf0.u[2] = u10; pf0.u[3] = u11;
    pf1.u[0] = u20; pf1.u[1] = u21; pf1.u[2] = u30; pf1.u[3] = u31;

    // PV: O^T[d][q] += V^T[d][k] * P[k][q]
    __builtin_amdgcn_s_setprio(1);
#pragma unroll
    for (int dh = 0; dh < 2; ++dh) {
      const int vrow = dh * 32 + li;
      const unsigned short* Vrow = Vc + vrow * 64;
      const int vsw = vrow & 7;
      const bf16x8 vf0 = *(const bf16x8*)(Vrow + (((hf * 4 + 0 + hi) ^ vsw) * 8));
      const bf16x8 vf1 = *(const bf16x8*)(Vrow + (((hf * 4 + 2 + hi) ^ vsw) * 8));
      if (dh == 0) {
        oa0 = __builtin_amdgcn_mfma_f32_32x32x16_bf16(vf0, pf0.v, oa0, 0, 0, 0);
        oa0 = __builtin_amdgcn_mfma_f32_32x32x16_bf16(vf1, pf1.v, oa0, 0, 0, 0);
      } else {
        oa1 = __builtin_amdgcn_mfma_f32_32x32x16_bf16(vf0, pf0.v, oa1, 0, 0, 0);
        oa1 = __builtin_amdgcn_mfma_f32_32x32x16_bf16(vf1, pf1.v, oa1, 0, 0, 0);
      }
    }
    __builtin_amdgcn_s_setprio(0);

    __syncthreads();   // drains stage loads; next buffer ready
  }
#undef STAGE

  // den over hi halves (within wave)
  den += __shfl_xor(den, 32);

  // combine wave pairs (hf=0/1) via LDS: Obuf reuses Ks (16KB), Dbuf reuses Vs
  float* Obuf = (float*)&Ks[0][0];   // [2 qg][32 slot][64 lane]
  float* Dbuf = (float*)&Vs[0][0];   // [2 qg][64 lane]
  if (hf == 1) {
#pragma unroll
    for (int r = 0; r < 16; ++r) {
      Obuf[(qg * 32 + r) * 64 + lane]      = oa0[r];
      Obuf[(qg * 32 + 16 + r) * 64 + lane] = oa1[r];
    }
    Dbuf[qg * 64 + lane] = den;
  }
  __syncthreads();
  if (hf == 0) {
    const float inv = 1.f / (den + Dbuf[qg * 64 + lane]);
    unsigned short* orow = Obf + (size_t)(b * 2048 + qrow) * 1024 + h * 64;
#pragma unroll
    for (int dh = 0; dh < 2; ++dh)
#pragma unroll
      for (int w = 0; w < 4; ++w) {
        float v0, v1, v2, v3;
        if (dh == 0) {
          v0 = oa0[4 * w];     v1 = oa0[4 * w + 1];
          v2 = oa0[4 * w + 2]; v3 = oa0[4 * w + 3];
        } else {
          v0 = oa1[4 * w];     v1 = oa1[4 * w + 1];
          v2 = oa1[4 * w + 2]; v3 = oa1[4 * w + 3];
        }
        const int sbase = (qg * 32 + dh * 16 + 4 * w) * 64 + lane;
        v0 += Obuf[sbase];       v1 += Obuf[sbase + 64];
        v2 += Obuf[sbase + 128]; v3 += Obuf[sbase + 192];
        ushort4 o4;
        o4.x = f2bf(v0 * inv); o4.y = f2bf(v1 * inv);
        o4.z = f2bf(v2 * inv); o4.w = f2bf(v3 * inv);
        // d = 32*dh + 8*w + 4*hi + i
        *(ushort4*)(orow + dh * 32 + w * 8 + hi * 4) = o4;
      }
  }
}

extern "C" void kernel_launch(void* const* d_in, const int* in_sizes, int n_in,
                              void* d_out, int out_size, void* d_ws, size_t ws_size,
                              hipStream_t stream) {
  const float* x  = (const float*)d_in[0];
  const float* Wq = (const float*)d_in[1];
  const float* Wk = (const float*)d_in[2];
  const float* Wv = (const float*)d_in[3];
  const float* Wo = (const float*)d_in[4];
  const int* mask = (const int*)d_in[5];

  unsigned short* ws = (unsigned short*)d_ws;
  const size_t SZ = 4194304;                 // 4096*1024
  unsigned short* xbf = ws;
  unsigned short* Wbf = ws + SZ;             // Wq,Wk,Wv,Wo @ +0/+1M/+2M/+3M
  unsigned short* Qbf = ws + 2 * SZ;
  unsigned short* Kbf = ws + 3 * SZ;         // must be Qbf + SZ (gemm mode 0 relies on it)
  unsigned short* Vt  = ws + 4 * SZ;         // [bh][64][2048]
  unsigned short* Obf = ws + 5 * SZ;
  float* qsqp = (float*)(ws + 6 * SZ);
  float* ksqp = qsqp + 65536;
  float* maskf = ksqp + 65536;

  // 1) f32 -> bf16
  cvt_kernel<<<4096, 256, 0, stream>>>(x,  xbf,            1048576);
  cvt_kernel<<<1024, 256, 0, stream>>>(Wq, Wbf,            262144);
  cvt_kernel<<<1024, 256, 0, stream>>>(Wk, Wbf + 1048576,  262144);
  cvt_kernel<<<1024, 256, 0, stream>>>(Wv, Wbf + 2097152,  262144);
  cvt_kernel<<<1024, 256, 0, stream>>>(Wo, Wbf + 3145728,  262144);

  // 2) fused QKV projection: x @ [Wq;Wk;Wv]^T  (Q prescaled by 2c)
  gemm_bt<<<dim3(32, 24), 256, 0, stream>>>(xbf, Wbf, Qbf, 1024, 0);

  // 3) -c*|q|^2 / -c*|k|^2 / mask->float
  rowsq_kernel<<<dim3(256, 2), 256, 0, stream>>>(Qbf, Kbf, mask, qsqp, ksqp, maskf);

  // 4) fused RBF attention -> Obf (bf16, [token][e] with e = h*64+d)
  attn_kernel<<<dim3(32, 32), 256, 0, stream>>>(Qbf, Kbf, Vt, qsqp, ksqp, maskf, Obf);

  // 5) output projection: Obf @ Wo^T -> f32 d_out
  gemm_bt<<<dim3(32, 8), 256, 0, stream>>>(Obf, Wbf + 3145728, d_out, 1024, 1);
}

// Round 4
// 140.059 us; speedup vs baseline: 2.4471x; 1.3569x over previous
//
#include <hip/hip_runtime.h>
#include <hip/hip_bf16.h>

// Problem constants: B=2, N=2048, E=1024, H=16, D_K=64, GAMMA=1
//   tokens M = 4096, K = 1024
//
// ws layout (ushort elems), SZ = 4096*1024 = 4194304:
//   xbf[SZ] | Wbf[SZ] (Wq,Wk,Wv,Wo @ +0/+1M/+2M/+3M) | Qbf[SZ] | Kbf[SZ]
//   | Vt[SZ] ([bh][64][2048]) | Obf[SZ]
//   | qsqp[64K f32] ksqp[64K f32] maskf[4K] FullVm[2K] den_base[2] kmaxb[32]
//
// Numerics: Qbf holds 2c*q (c = log2 e). qsqp = -c*|q|^2, ksqp = -c*|k|^2.
// z = qsqp + ksqp + 2c*qk = -c*d; sim s = 2^z = exp(-d) in [0,1].
// Softmax weight p = e^s * m  =  m + m*expm1(s).
//   O = FullVm + Sum_slow V*(m*expm1(s));  den = den_base + Sum_slow m*expm1(s)
// Tiles with max z < -14 contribute only their m-part (error < 6e-5/score).
// Classification uses conservative bound z <= st_raw + qsl + kmax_bh.

using bf16x8 = __attribute__((ext_vector_type(8))) __bf16;
using f32x4  = __attribute__((ext_vector_type(4))) float;
using f32x16 = __attribute__((ext_vector_type(16))) float;

typedef const __attribute__((address_space(1))) void* gas_t;
typedef __attribute__((address_space(3))) void* las_t;

#define C_LOG2E 1.4426950408889634f
#define TWO_C   2.8853900817779268f
#define NEG_INV_4C (-0.17328679513998632f)

#if __has_builtin(__builtin_amdgcn_exp2f)
#define EXP2(x) __builtin_amdgcn_exp2f(x)
#else
#define EXP2(x) __expf((x) * 0.6931471805599453f)
#endif

static __device__ __forceinline__ unsigned short f2bf(float x) {
  union { float f; unsigned u; } c; c.f = x;
  unsigned u = c.u;
  u += 0x7fffu + ((u >> 16) & 1u);          // round-to-nearest-even
  return (unsigned short)(u >> 16);
}
static __device__ __forceinline__ float bf2f(unsigned short b) {
  union { unsigned u; float f; } c; c.u = ((unsigned)b) << 16;
  return c.f;
}
static __device__ __forceinline__ unsigned cvt_pk_bf16(float lo, float hi) {
  unsigned r;
  asm("v_cvt_pk_bf16_f32 %0, %1, %2" : "=v"(r) : "v"(lo), "v"(hi));
  return r;
}
static __device__ __forceinline__ void permlane32_swap(unsigned &a, unsigned &b) {
#if __has_builtin(__builtin_amdgcn_permlane32_swap)
  auto r = __builtin_amdgcn_permlane32_swap(a, b, false, false);
  a = r[0]; b = r[1];
#else
  asm("v_permlane32_swap_b32 %0, %1" : "+v"(a), "+v"(b));
#endif
}

// ---------------- f32 -> bf16 convert (vector x4) ----------------
__global__ __launch_bounds__(256)
void cvt_kernel(const float* __restrict__ in, unsigned short* __restrict__ out, int n4) {
  int idx = blockIdx.x * 256 + threadIdx.x;
  if (idx >= n4) return;
  float4 v = ((const float4*)in)[idx];
  ushort4 o;
  o.x = f2bf(v.x); o.y = f2bf(v.y); o.z = f2bf(v.z); o.w = f2bf(v.w);
  ((ushort4*)out)[idx] = o;
}

// ---------------- GEMM: C[M][Ncols] = A[M][K] * Bt[Ncols][K]^T ----------------
// m97 structure: 128x128 tile, 4 waves (2x2), BK=32, global_load_lds width 16.
__global__ __launch_bounds__(256)
void gemm_bt(const unsigned short* __restrict__ A,
             const unsigned short* __restrict__ Bt,
             void* __restrict__ out0, int Kdim, int mode) {
  __shared__ unsigned short As[4096];   // [128][32]
  __shared__ unsigned short Bs[4096];   // [128][32]
  const int t  = threadIdx.x;
  const int m0 = blockIdx.x * 128;
  const int n0 = blockIdx.y * 128;
  const int srow = t >> 2;
  const int scol = (t & 3) * 8;
  const unsigned short* pA = A  + (size_t)(m0 + srow) * Kdim + scol;
  const unsigned short* pB = Bt + (size_t)(n0 + srow) * Kdim + scol;
  const size_t rowskip = (size_t)64 * Kdim;

  const int wave = t >> 6, lane = t & 63;
  const int wm = (wave >> 1) * 64, wn = (wave & 1) * 64;
  const int fr = lane & 15, fg = lane >> 4;
  const int aoff = (wm + fr) * 32 + fg * 8;
  const int boff = (wn + fr) * 32 + fg * 8;

  f32x4 acc[4][4];
#pragma unroll
  for (int mi = 0; mi < 4; ++mi)
#pragma unroll
    for (int ni = 0; ni < 4; ++ni)
      acc[mi][ni] = (f32x4){0.f, 0.f, 0.f, 0.f};

  for (int k0 = 0; k0 < Kdim; k0 += 32) {
    __builtin_amdgcn_global_load_lds((gas_t)(const void*)pA,             (las_t)(void*)(As + t * 8),        16, 0, 0);
    __builtin_amdgcn_global_load_lds((gas_t)(const void*)(pA + rowskip), (las_t)(void*)(As + 2048 + t * 8), 16, 0, 0);
    __builtin_amdgcn_global_load_lds((gas_t)(const void*)pB,             (las_t)(void*)(Bs + t * 8),        16, 0, 0);
    __builtin_amdgcn_global_load_lds((gas_t)(const void*)(pB + rowskip), (las_t)(void*)(Bs + 2048 + t * 8), 16, 0, 0);
    pA += 32; pB += 32;
    __syncthreads();

    bf16x8 af[4], bfr[4];
#pragma unroll
    for (int mi = 0; mi < 4; ++mi) af[mi]  = *(const bf16x8*)(As + aoff + mi * 512);
#pragma unroll
    for (int ni = 0; ni < 4; ++ni) bfr[ni] = *(const bf16x8*)(Bs + boff + ni * 512);
#pragma unroll
    for (int mi = 0; mi < 4; ++mi)
#pragma unroll
      for (int ni = 0; ni < 4; ++ni)
        acc[mi][ni] = __builtin_amdgcn_mfma_f32_16x16x32_bf16(af[mi], bfr[ni], acc[mi][ni], 0, 0, 0);
    __syncthreads();
  }

  // epilogue: C/D layout col = lane&15, row = (lane>>4)*4 + r  [m89-verified]
#pragma unroll
  for (int mi = 0; mi < 4; ++mi) {
    const int gm = m0 + wm + mi * 16 + fg * 4;
#pragma unroll
    for (int ni = 0; ni < 4; ++ni) {
      const int gn = n0 + wn + ni * 16 + fr;
      if (mode == 0) {
        unsigned short* outw = (unsigned short*)out0;
        const int z = gn >> 10, col = gn & 1023;
        if (z < 2) {                                   // Q (scaled by 2c) or K
          const float sc = (z == 0) ? TWO_C : 1.0f;
          unsigned short* dst = outw + (size_t)z * 4194304u;
#pragma unroll
          for (int r = 0; r < 4; ++r)
            dst[(size_t)(gm + r) * 1024 + col] = f2bf(acc[mi][ni][r] * sc);
        } else {                                       // V -> Vt[bh][d][n]
          ushort4 o4;
          o4.x = f2bf(acc[mi][ni][0]); o4.y = f2bf(acc[mi][ni][1]);
          o4.z = f2bf(acc[mi][ni][2]); o4.w = f2bf(acc[mi][ni][3]);
          const int bb = gm >> 11, nn = gm & 2047;
          const int hh = col >> 6, dd = col & 63;
          unsigned short* vt = outw + (size_t)2 * 4194304u;
          *(ushort4*)(vt + ((size_t)((bb * 16 + hh) * 64 + dd)) * 2048 + nn) = o4;
        }
      } else {                                         // f32 out
        float* dst = (float*)out0;
#pragma unroll
        for (int r = 0; r < 4; ++r)
          dst[(size_t)(gm + r) * 1024 + gn] = acc[mi][ni][r];
      }
    }
  }
}

// ---------------- per-(bh,n) scaled row sumsq + mask->float ----------------
__global__ __launch_bounds__(256)
void rowsq_kernel(const unsigned short* __restrict__ Qbf,
                  const unsigned short* __restrict__ Kbf,
                  const int* __restrict__ mask,
                  float* __restrict__ qsqp, float* __restrict__ ksqp,
                  float* __restrict__ maskf) {
  const int tid = blockIdx.x * 256 + threadIdx.x;     // 0..65535 = bh*2048 + n
  const int kpath = blockIdx.y;
  const unsigned short* src = (kpath == 0) ? Qbf : Kbf;
  const int bh = tid >> 11, n = tid & 2047;
  const int b = bh >> 4, h = bh & 15;
  const unsigned short* row = src + (size_t)(b * 2048 + n) * 1024 + h * 64;
  float s = 0.f;
#pragma unroll
  for (int c = 0; c < 64; c += 4) {
    ushort4 v = *(const ushort4*)(row + c);
    float f0 = bf2f(v.x), f1 = bf2f(v.y), f2 = bf2f(v.z), f3 = bf2f(v.w);
    s += f0 * f0 + f1 * f1 + f2 * f2 + f3 * f3;
  }
  if (kpath == 0) {
    qsqp[tid] = s * NEG_INV_4C;      // Q was prescaled by 2c: -c*|q|^2 = -s/(4c)
  } else {
    ksqp[tid] = s * (-C_LOG2E);
    if (tid < 4096) maskf[tid] = (mask[tid] == 0) ? 0.f : 1.f;
  }
}

// ---------------- precompute: FullVm[bh][d], kmaxb[bh], den_base[b] ----------------
__global__ __launch_bounds__(256)
void prep_kernel(const unsigned short* __restrict__ Vt,
                 const float* __restrict__ maskf,
                 const float* __restrict__ ksqp,
                 float* __restrict__ FullVm,
                 float* __restrict__ den_base,
                 float* __restrict__ kmaxb) {
  const int bh = blockIdx.x;          // 0..31
  const int b = bh >> 4;
  const int wave = threadIdx.x >> 6, lane = threadIdx.x & 63;
  // FullVm[bh][d] = sum_k m[k] * V[k][d]  (from Vt[bh][d][k])
  for (int dr = wave * 16; dr < wave * 16 + 16; ++dr) {
    const unsigned short* row = Vt + ((size_t)bh * 64 + dr) * 2048 + lane * 32;
    const float* mrow = maskf + b * 2048 + lane * 32;
    float s = 0.f;
#pragma unroll
    for (int c = 0; c < 32; c += 4) {
      ushort4 v = *(const ushort4*)(row + c);
      float4 m = *(const float4*)(mrow + c);
      s += bf2f(v.x) * m.x + bf2f(v.y) * m.y + bf2f(v.z) * m.z + bf2f(v.w) * m.w;
    }
#pragma unroll
    for (int off = 32; off >= 1; off >>= 1) s += __shfl_xor(s, off);
    if (lane == 0) FullVm[bh * 64 + dr] = s;
  }
  if (wave == 0) {                    // kmaxb[bh] = max_k ksqp
    const float* kp = ksqp + bh * 2048 + lane;
    float mx = -3.0e38f;
    for (int c = 0; c < 2048; c += 64) mx = fmaxf(mx, kp[c]);
#pragma unroll
    for (int off = 32; off >= 1; off >>= 1) mx = fmaxf(mx, __shfl_xor(mx, off));
    if (lane == 0) kmaxb[bh] = mx;
  }
  if (wave == 1 && (bh == 0 || bh == 16)) {   // den_base[b] = sum m
    const float* mrow = maskf + b * 2048 + lane;
    float s = 0.f;
    for (int c = 0; c < 2048; c += 64) s += mrow[c];
#pragma unroll
    for (int off = 32; off >= 1; off >>= 1) s += __shfl_xor(s, off);
    if (lane == 0) den_base[b] = s;
  }
}

// ---------------- fused RBF attention, classify-and-skip ----------------
// grid (32 bh, 32 qtiles), 4 waves: wave = qg*2 + hf. K-only LDS staging
// (double-buffered, swizzled). Fast tiles: QK MFMA + max-test only.
__global__ __launch_bounds__(256)
void attn_kernel(const unsigned short* __restrict__ Qbf,
                 const unsigned short* __restrict__ Kbf,
                 const unsigned short* __restrict__ Vt,
                 const float* __restrict__ qsqp,
                 const float* __restrict__ ksqp,
                 const float* __restrict__ maskf,
                 const float* __restrict__ FullVm,
                 const float* __restrict__ den_base,
                 const float* __restrict__ kmaxb,
                 unsigned short* __restrict__ Obf) {
  __shared__ unsigned short Ks[2][4096];   // [buf][64 k][64 d] swizzled (chunk^=row&7)
  __shared__ float Obuf[2][32][64];
  __shared__ float Dbuf[2][64];

  const int bh = blockIdx.x;
  const int b = bh >> 4, h = bh & 15;
  const int t = threadIdx.x;
  const int wave = t >> 6, lane = t & 63;
  const int qg = wave >> 1, hf = wave & 1;
  const int li = lane & 31, hi = lane >> 5;
  const int q0 = blockIdx.y * 64 + qg * 32;
  const int qrow = q0 + li;

  // Q fragments: B-operand, lane holds Q[qrow][dblk*16 + hi*8 + e]
  const unsigned short* Qr = Qbf + (size_t)(b * 2048 + qrow) * 1024 + h * 64 + hi * 8;
  bf16x8 qf[4];
#pragma unroll
  for (int dblk = 0; dblk < 4; ++dblk) qf[dblk] = *(const bf16x8*)(Qr + dblk * 16);

  const float qsl = qsqp[bh * 2048 + qrow];
  const float thr = -14.0f - qsl - kmaxb[bh];   // st_raw > thr possible => slow path

  const unsigned short* Kbase = Kbf + (size_t)b * 2048 * 1024 + h * 64;
  const unsigned short* VtB = Vt + (size_t)bh * 64 * 2048;

  // staging: chunk p (16B) of an 8KB K tile; row = p>>3, slot cp = p&7 holds
  // logical chunk cl = cp ^ (row&7)  (read side XORs the same way).
  const int p0 = t,        r0 = p0 >> 3, c0 = (p0 & 7) ^ (r0 & 7);
  const int p1 = 256 + t,  r1 = p1 >> 3, c1 = (p1 & 7) ^ (r1 & 7);

  f32x16 oa0, oa1;
#pragma unroll
  for (int r = 0; r < 16; ++r) { oa0[r] = 0.f; oa1[r] = 0.f; }
  float den = 0.f;

#define STAGE(bi, tj)                                                                               \
  do {                                                                                              \
    const int j0s = (tj) * 64;                                                                      \
    __builtin_amdgcn_global_load_lds((gas_t)(const void*)(Kbase + (size_t)(j0s + r0) * 1024 + c0 * 8), \
                                     (las_t)(void*)(Ks[bi] + p0 * 8), 16, 0, 0);                    \
    __builtin_amdgcn_global_load_lds((gas_t)(const void*)(Kbase + (size_t)(j0s + r1) * 1024 + c1 * 8), \
                                     (las_t)(void*)(Ks[bi] + p1 * 8), 16, 0, 0);                    \
  } while (0)

  STAGE(0, 0);
  __syncthreads();

  const int jw = hf * 32;            // this wave's k-offset within the 64-k tile
  const int krow = jw + li;          // K LDS row
  const int ksw = krow & 7;

  for (int tj = 0; tj < 32; ++tj) {
    const int cur = tj & 1;
    if (tj + 1 < 32) STAGE(cur ^ 1, tj + 1);

    // QK^T raw: st = K_tile * Q^T (C-init 0); z = st + qsl + ksq'
    const unsigned short* Krow = Ks[cur] + krow * 64;
    f32x16 st;
#pragma unroll
    for (int r = 0; r < 16; ++r) st[r] = 0.f;
#pragma unroll
    for (int dblk = 0; dblk < 4; ++dblk) {
      const bf16x8 kf = *(const bf16x8*)(Krow + ((dblk * 2 + hi) ^ ksw) * 8);
      st = __builtin_amdgcn_mfma_f32_32x32x16_bf16(kf, qf[dblk], st, 0, 0, 0);
    }

    // max tree (max3-friendly)
    const float a0 = fmaxf(fmaxf(st[0], st[1]), st[2]);
    const float a1 = fmaxf(fmaxf(st[3], st[4]), st[5]);
    const float a2 = fmaxf(fmaxf(st[6], st[7]), st[8]);
    const float a3 = fmaxf(fmaxf(st[9], st[10]), st[11]);
    const float a4 = fmaxf(fmaxf(st[12], st[13]), st[14]);
    const float a5 = fmaxf(fmaxf(a0, a1), st[15]);
    const float a6 = fmaxf(fmaxf(a2, a3), a4);
    const float lmax = fmaxf(a5, a6);

    if (__any(lmax > thr)) {
      // ---- slow path (rare): ds = m * expm1(2^z), z = st + qsl + ksq' ----
      const int j0 = tj * 64 + jw;
      const float* ksb2 = ksqp + bh * 2048 + j0 + 4 * hi;
      const float* mfb2 = maskf + b * 2048 + j0 + 4 * hi;
      const float4 kq0 = *(const float4*)(ksb2);
      const float4 kq1 = *(const float4*)(ksb2 + 8);
      const float4 kq2 = *(const float4*)(ksb2 + 16);
      const float4 kq3 = *(const float4*)(ksb2 + 24);
      const float4 mf0 = *(const float4*)(mfb2);
      const float4 mf1 = *(const float4*)(mfb2 + 8);
      const float4 mf2 = *(const float4*)(mfb2 + 16);
      const float4 mf3 = *(const float4*)(mfb2 + 24);
      const float kqa[16] = {kq0.x, kq0.y, kq0.z, kq0.w, kq1.x, kq1.y, kq1.z, kq1.w,
                             kq2.x, kq2.y, kq2.z, kq2.w, kq3.x, kq3.y, kq3.z, kq3.w};
      const float mfa[16] = {mf0.x, mf0.y, mf0.z, mf0.w, mf1.x, mf1.y, mf1.z, mf1.w,
                             mf2.x, mf2.y, mf2.z, mf2.w, mf3.x, mf3.y, mf3.z, mf3.w};
      float dsv[16];
#pragma unroll
      for (int r = 0; r < 16; ++r) {
        const float z = __builtin_fminf(st[r] + qsl + kqa[r], 0.f);
        const float s = EXP2(z);
        // expm1(s)/s = 1 + s/2 + s^2/6 + s^3/24 + s^4/120
        float pl = __builtin_fmaf(s, 1.f / 120.f, 1.f / 24.f);
        pl = __builtin_fmaf(s, pl, 1.f / 6.f);
        pl = __builtin_fmaf(s, pl, 0.5f);
        pl = __builtin_fmaf(s, pl, 1.f);
        const float d_ = s * pl * mfa[r];
        dsv[r] = d_;
        den += d_;
      }

      // P redistribution: cvt_pk pairs, permlane32_swap -> B-fragments
      unsigned u00 = cvt_pk_bf16(dsv[0],  dsv[1]);
      unsigned u01 = cvt_pk_bf16(dsv[2],  dsv[3]);
      unsigned u10 = cvt_pk_bf16(dsv[4],  dsv[5]);
      unsigned u11 = cvt_pk_bf16(dsv[6],  dsv[7]);
      unsigned u20 = cvt_pk_bf16(dsv[8],  dsv[9]);
      unsigned u21 = cvt_pk_bf16(dsv[10], dsv[11]);
      unsigned u30 = cvt_pk_bf16(dsv[12], dsv[13]);
      unsigned u31 = cvt_pk_bf16(dsv[14], dsv[15]);
      permlane32_swap(u00, u10);
      permlane32_swap(u01, u11);
      permlane32_swap(u20, u30);
      permlane32_swap(u21, u31);
      union { unsigned u[4]; bf16x8 v; } pf0, pf1;
      pf0.u[0] = u00; pf0.u[1] = u01; pf0.u[2] = u10; pf0.u[3] = u11;
      pf1.u[0] = u20; pf1.u[1] = u21; pf1.u[2] = u30; pf1.u[3] = u31;

      // PV: O^T[d][q] += V^T[d][k] * dP[k][q];  V direct from global (L2-hit)
#pragma unroll
      for (int dh = 0; dh < 2; ++dh) {
        const unsigned short* Vrow = VtB + (size_t)(dh * 32 + li) * 2048 + tj * 64;
        const bf16x8 vf0 = *(const bf16x8*)(Vrow + (hf * 4 + 0 + hi) * 8);
        const bf16x8 vf1 = *(const bf16x8*)(Vrow + (hf * 4 + 2 + hi) * 8);
        if (dh == 0) {
          oa0 = __builtin_amdgcn_mfma_f32_32x32x16_bf16(vf0, pf0.v, oa0, 0, 0, 0);
          oa0 = __builtin_amdgcn_mfma_f32_32x32x16_bf16(vf1, pf1.v, oa0, 0, 0, 0);
        } else {
          oa1 = __builtin_amdgcn_mfma_f32_32x32x16_bf16(vf0, pf0.v, oa1, 0, 0, 0);
          oa1 = __builtin_amdgcn_mfma_f32_32x32x16_bf16(vf1, pf1.v, oa1, 0, 0, 0);
        }
      }
    }

    __syncthreads();   // drains stage loads; next buffer ready
  }
#undef STAGE

  // den over hi halves (within wave)
  den += __shfl_xor(den, 32);

  // combine wave pairs (hf=0/1) via LDS
  if (hf == 1) {
#pragma unroll
    for (int r = 0; r < 16; ++r) {
      Obuf[qg][r][lane]      = oa0[r];
      Obuf[qg][16 + r][lane] = oa1[r];
    }
    Dbuf[qg][lane] = den;
  }
  __syncthreads();
  if (hf == 0) {
    const float inv = 1.f / (den_base[b] + den + Dbuf[qg][lane]);
    const float* fvm = FullVm + bh * 64;
    unsigned short* orow = Obf + (size_t)(b * 2048 + qrow) * 1024 + h * 64;
#pragma unroll
    for (int dh = 0; dh < 2; ++dh)
#pragma unroll
      for (int w = 0; w < 4; ++w) {
        float v0, v1, v2, v3;
        if (dh == 0) {
          v0 = oa0[4 * w];     v1 = oa0[4 * w + 1];
          v2 = oa0[4 * w + 2]; v3 = oa0[4 * w + 3];
        } else {
          v0 = oa1[4 * w];     v1 = oa1[4 * w + 1];
          v2 = oa1[4 * w + 2]; v3 = oa1[4 * w + 3];
        }
        v0 += Obuf[qg][dh * 16 + 4 * w + 0][lane];
        v1 += Obuf[qg][dh * 16 + 4 * w + 1][lane];
        v2 += Obuf[qg][dh * 16 + 4 * w + 2][lane];
        v3 += Obuf[qg][dh * 16 + 4 * w + 3][lane];
        // d = 32*dh + 8*w + 4*hi + i
        const float4 fv = *(const float4*)(fvm + dh * 32 + w * 8 + hi * 4);
        ushort4 o4;
        o4.x = f2bf((v0 + fv.x) * inv);
        o4.y = f2bf((v1 + fv.y) * inv);
        o4.z = f2bf((v2 + fv.z) * inv);
        o4.w = f2bf((v3 + fv.w) * inv);
        *(ushort4*)(orow + dh * 32 + w * 8 + hi * 4) = o4;
      }
  }
}

extern "C" void kernel_launch(void* const* d_in, const int* in_sizes, int n_in,
                              void* d_out, int out_size, void* d_ws, size_t ws_size,
                              hipStream_t stream) {
  const float* x  = (const float*)d_in[0];
  const float* Wq = (const float*)d_in[1];
  const float* Wk = (const float*)d_in[2];
  const float* Wv = (const float*)d_in[3];
  const float* Wo = (const float*)d_in[4];
  const int* mask = (const int*)d_in[5];

  unsigned short* ws = (unsigned short*)d_ws;
  const size_t SZ = 4194304;                 // 4096*1024
  unsigned short* xbf = ws;
  unsigned short* Wbf = ws + SZ;             // Wq,Wk,Wv,Wo @ +0/+1M/+2M/+3M
  unsigned short* Qbf = ws + 2 * SZ;
  unsigned short* Kbf = ws + 3 * SZ;         // must be Qbf + SZ (gemm mode 0 relies on it)
  unsigned short* Vt  = ws + 4 * SZ;         // [bh][64][2048]
  unsigned short* Obf = ws + 5 * SZ;
  float* qsqp = (float*)(ws + 6 * SZ);
  float* ksqp = qsqp + 65536;
  float* maskf = ksqp + 65536;
  float* FullVm = maskf + 4096;
  float* den_base = FullVm + 2048;
  float* kmaxb = den_base + 2;

  // 1) f32 -> bf16
  cvt_kernel<<<4096, 256, 0, stream>>>(x,  xbf,            1048576);
  cvt_kernel<<<1024, 256, 0, stream>>>(Wq, Wbf,            262144);
  cvt_kernel<<<1024, 256, 0, stream>>>(Wk, Wbf + 1048576,  262144);
  cvt_kernel<<<1024, 256, 0, stream>>>(Wv, Wbf + 2097152,  262144);
  cvt_kernel<<<1024, 256, 0, stream>>>(Wo, Wbf + 3145728,  262144);

  // 2) fused QKV projection: x @ [Wq;Wk;Wv]^T  (Q prescaled by 2c)
  gemm_bt<<<dim3(32, 24), 256, 0, stream>>>(xbf, Wbf, Qbf, 1024, 0);

  // 3) -c*|q|^2 / -c*|k|^2 / mask->float
  rowsq_kernel<<<dim3(256, 2), 256, 0, stream>>>(Qbf, Kbf, mask, qsqp, ksqp, maskf);

  // 4) precompute FullVm / den_base / kmaxb
  prep_kernel<<<32, 256, 0, stream>>>(Vt, maskf, ksqp, FullVm, den_base, kmaxb);

  // 5) fused RBF attention -> Obf
  attn_kernel<<<dim3(32, 32), 256, 0, stream>>>(Qbf, Kbf, Vt, qsqp, ksqp, maskf,
                                                FullVm, den_base, kmaxb, Obf);

  // 6) output projection: Obf @ Wo^T -> f32 d_out
  gemm_bt<<<dim3(32, 8), 256, 0, stream>>>(Obf, Wbf + 3145728, d_out, 1024, 1);
}

// Round 5
// 123.687 us; speedup vs baseline: 2.7710x; 1.1324x over previous
//
#include <hip/hip_runtime.h>
#include <hip/hip_bf16.h>

// Problem constants: B=2, N=2048, E=1024, H=16, D_K=64, GAMMA=1
//   tokens M = 4096, K = 1024
//
// ws layout (ushort elems), SZ = 4096*1024 = 4194304:
//   xbf[SZ] | Wbf[SZ] (Wq,Wk,Wv,Wo @ +0/+1M/+2M/+3M) | Qbf[SZ] | Kbf[SZ]
//   | Vt[SZ] ([bh][64][2048]) | Obf[SZ]
//   | qsqp[64K f32] ksqp[64K f32] maskf[4K] FullVm[2K] den_base[2] kmaxb[32]
//
// Numerics: Qbf holds 2c*q (c = log2 e). qsqp = -c*|q|^2, ksqp = -c*|k|^2.
// z = qsqp + ksqp + 2c*qk = -c*d; sim s = 2^z = exp(-d) in [0,1].
// Softmax weight p = e^s * m  =  m + m*expm1(s).
//   O = FullVm + Sum_slow V*(m*expm1(s));  den = den_base + Sum_slow m*expm1(s)
// Tiles with max z < -14 contribute only their m-part (error < 6e-5/score).

using bf16x8 = __attribute__((ext_vector_type(8))) __bf16;
using f32x4  = __attribute__((ext_vector_type(4))) float;
using f32x16 = __attribute__((ext_vector_type(16))) float;

typedef const __attribute__((address_space(1))) void* gas_t;
typedef __attribute__((address_space(3))) void* las_t;

#define C_LOG2E 1.4426950408889634f
#define TWO_C   2.8853900817779268f
#define NEG_INV_4C (-0.17328679513998632f)

#if __has_builtin(__builtin_amdgcn_exp2f)
#define EXP2(x) __builtin_amdgcn_exp2f(x)
#else
#define EXP2(x) __expf((x) * 0.6931471805599453f)
#endif

static __device__ __forceinline__ unsigned short f2bf(float x) {
  union { float f; unsigned u; } c; c.f = x;
  unsigned u = c.u;
  u += 0x7fffu + ((u >> 16) & 1u);          // round-to-nearest-even
  return (unsigned short)(u >> 16);
}
static __device__ __forceinline__ float bf2f(unsigned short b) {
  union { unsigned u; float f; } c; c.u = ((unsigned)b) << 16;
  return c.f;
}
static __device__ __forceinline__ unsigned cvt_pk_bf16(float lo, float hi) {
  unsigned r;
  asm("v_cvt_pk_bf16_f32 %0, %1, %2" : "=v"(r) : "v"(lo), "v"(hi));
  return r;
}
static __device__ __forceinline__ void permlane32_swap(unsigned &a, unsigned &b) {
#if __has_builtin(__builtin_amdgcn_permlane32_swap)
  auto r = __builtin_amdgcn_permlane32_swap(a, b, false, false);
  a = r[0]; b = r[1];
#else
  asm("v_permlane32_swap_b32 %0, %1" : "+v"(a), "+v"(b));
#endif
}

// ---------------- fused f32 -> bf16 convert for all 5 inputs ----------------
// grid 8192 x 256: idx is a float4-group index. [0,1M) = x; then 256K per W.
// All range boundaries are multiples of 256 -> block-uniform routing.
__global__ __launch_bounds__(256)
void cvt_all(const float* __restrict__ x,  const float* __restrict__ wq,
             const float* __restrict__ wk, const float* __restrict__ wv,
             const float* __restrict__ wo,
             unsigned short* __restrict__ xbf, unsigned short* __restrict__ Wbf) {
  const int idx = blockIdx.x * 256 + threadIdx.x;
  const float* src; unsigned short* dst; int off;
  if (idx < 1048576) { src = x; dst = xbf; off = idx; }
  else {
    const int r = idx - 1048576;
    const int w = r >> 18;                 // 262144 groups per W
    off = r & 262143;
    src = (w == 0) ? wq : (w == 1) ? wk : (w == 2) ? wv : wo;
    dst = Wbf + (size_t)w * 1048576u;
  }
  const float4 v = ((const float4*)src)[off];
  ushort4 o;
  o.x = f2bf(v.x); o.y = f2bf(v.y); o.z = f2bf(v.z); o.w = f2bf(v.w);
  ((ushort4*)dst)[off] = o;
}

// ---------------- GEMM: C[M][Ncols] = A[M][K] * Bt[Ncols][K]^T ----------------
// 128x128 tile, 4 waves (2x2), BK=32, global_load_lds width 16.
// T3-minimum 2-phase: double-buffered LDS, STAGE(next) issued BEFORE compute,
// one barrier per K-step (its vmcnt(0) drain lands after compute covered it).
__global__ __launch_bounds__(256)
void gemm_bt(const unsigned short* __restrict__ A,
             const unsigned short* __restrict__ Bt,
             void* __restrict__ out0, int Kdim, int mode) {
  __shared__ unsigned short As[2][4096];   // [buf][128][32]
  __shared__ unsigned short Bs[2][4096];
  const int t  = threadIdx.x;
  const int m0 = blockIdx.x * 128;
  const int n0 = blockIdx.y * 128;
  const int srow = t >> 2;
  const int scol = (t & 3) * 8;
  const unsigned short* pA = A  + (size_t)(m0 + srow) * Kdim + scol;
  const unsigned short* pB = Bt + (size_t)(n0 + srow) * Kdim + scol;
  const size_t rowskip = (size_t)64 * Kdim;

  const int wave = t >> 6, lane = t & 63;
  const int wm = (wave >> 1) * 64, wn = (wave & 1) * 64;
  const int fr = lane & 15, fg = lane >> 4;
  const int aoff = (wm + fr) * 32 + fg * 8;
  const int boff = (wn + fr) * 32 + fg * 8;

  f32x4 acc[4][4];
#pragma unroll
  for (int mi = 0; mi < 4; ++mi)
#pragma unroll
    for (int ni = 0; ni < 4; ++ni)
      acc[mi][ni] = (f32x4){0.f, 0.f, 0.f, 0.f};

#define GSTAGE(bi, kk)                                                                                  \
  do {                                                                                                  \
    const int kc = (kk) * 32;                                                                           \
    __builtin_amdgcn_global_load_lds((gas_t)(const void*)(pA + kc),           (las_t)(void*)(As[bi] + t * 8),        16, 0, 0); \
    __builtin_amdgcn_global_load_lds((gas_t)(const void*)(pA + kc + rowskip), (las_t)(void*)(As[bi] + 2048 + t * 8), 16, 0, 0); \
    __builtin_amdgcn_global_load_lds((gas_t)(const void*)(pB + kc),           (las_t)(void*)(Bs[bi] + t * 8),        16, 0, 0); \
    __builtin_amdgcn_global_load_lds((gas_t)(const void*)(pB + kc + rowskip), (las_t)(void*)(Bs[bi] + 2048 + t * 8), 16, 0, 0); \
  } while (0)

  const int NK = Kdim >> 5;
  GSTAGE(0, 0);
  __syncthreads();

  for (int ks = 0; ks < NK; ++ks) {
    const int cur = ks & 1;
    if (ks + 1 < NK) GSTAGE(cur ^ 1, ks + 1);

    bf16x8 af[4], bfr[4];
#pragma unroll
    for (int mi = 0; mi < 4; ++mi) af[mi]  = *(const bf16x8*)(As[cur] + aoff + mi * 512);
#pragma unroll
    for (int ni = 0; ni < 4; ++ni) bfr[ni] = *(const bf16x8*)(Bs[cur] + boff + ni * 512);
#pragma unroll
    for (int mi = 0; mi < 4; ++mi)
#pragma unroll
      for (int ni = 0; ni < 4; ++ni)
        acc[mi][ni] = __builtin_amdgcn_mfma_f32_16x16x32_bf16(af[mi], bfr[ni], acc[mi][ni], 0, 0, 0);
    __syncthreads();   // drains stage loads (flew under compute); next buf ready
  }
#undef GSTAGE

  // epilogue: C/D layout col = lane&15, row = (lane>>4)*4 + r  [m89-verified]
#pragma unroll
  for (int mi = 0; mi < 4; ++mi) {
    const int gm = m0 + wm + mi * 16 + fg * 4;
#pragma unroll
    for (int ni = 0; ni < 4; ++ni) {
      const int gn = n0 + wn + ni * 16 + fr;
      if (mode == 0) {
        unsigned short* outw = (unsigned short*)out0;
        const int z = gn >> 10, col = gn & 1023;
        if (z < 2) {                                   // Q (scaled by 2c) or K
          const float sc = (z == 0) ? TWO_C : 1.0f;
          unsigned short* dst = outw + (size_t)z * 4194304u;
#pragma unroll
          for (int r = 0; r < 4; ++r)
            dst[(size_t)(gm + r) * 1024 + col] = f2bf(acc[mi][ni][r] * sc);
        } else {                                       // V -> Vt[bh][d][n]
          ushort4 o4;
          o4.x = f2bf(acc[mi][ni][0]); o4.y = f2bf(acc[mi][ni][1]);
          o4.z = f2bf(acc[mi][ni][2]); o4.w = f2bf(acc[mi][ni][3]);
          const int bb = gm >> 11, nn = gm & 2047;
          const int hh = col >> 6, dd = col & 63;
          unsigned short* vt = outw + (size_t)2 * 4194304u;
          *(ushort4*)(vt + ((size_t)((bb * 16 + hh) * 64 + dd)) * 2048 + nn) = o4;
        }
      } else {                                         // f32 out
        float* dst = (float*)out0;
#pragma unroll
        for (int r = 0; r < 4; ++r)
          dst[(size_t)(gm + r) * 1024 + gn] = acc[mi][ni][r];
      }
    }
  }
}

// ---------------- per-(bh,n) scaled row sumsq + mask->float ----------------
__global__ __launch_bounds__(256)
void rowsq_kernel(const unsigned short* __restrict__ Qbf,
                  const unsigned short* __restrict__ Kbf,
                  const int* __restrict__ mask,
                  float* __restrict__ qsqp, float* __restrict__ ksqp,
                  float* __restrict__ maskf) {
  const int tid = blockIdx.x * 256 + threadIdx.x;     // 0..65535 = bh*2048 + n
  const int kpath = blockIdx.y;
  const unsigned short* src = (kpath == 0) ? Qbf : Kbf;
  const int bh = tid >> 11, n = tid & 2047;
  const int b = bh >> 4, h = bh & 15;
  const unsigned short* row = src + (size_t)(b * 2048 + n) * 1024 + h * 64;
  float s = 0.f;
#pragma unroll
  for (int c = 0; c < 64; c += 4) {
    ushort4 v = *(const ushort4*)(row + c);
    float f0 = bf2f(v.x), f1 = bf2f(v.y), f2 = bf2f(v.z), f3 = bf2f(v.w);
    s += f0 * f0 + f1 * f1 + f2 * f2 + f3 * f3;
  }
  if (kpath == 0) {
    qsqp[tid] = s * NEG_INV_4C;      // Q was prescaled by 2c: -c*|q|^2 = -s/(4c)
  } else {
    ksqp[tid] = s * (-C_LOG2E);
    if (tid < 4096) maskf[tid] = (mask[tid] == 0) ? 0.f : 1.f;
  }
}

// ---------------- precompute: FullVm[bh][d], kmaxb[bh], den_base[b] ----------------
__global__ __launch_bounds__(256)
void prep_kernel(const unsigned short* __restrict__ Vt,
                 const float* __restrict__ maskf,
                 const float* __restrict__ ksqp,
                 float* __restrict__ FullVm,
                 float* __restrict__ den_base,
                 float* __restrict__ kmaxb) {
  const int bh = blockIdx.x;          // 0..31
  const int b = bh >> 4;
  const int wave = threadIdx.x >> 6, lane = threadIdx.x & 63;
  // FullVm[bh][d] = sum_k m[k] * V[k][d]  (from Vt[bh][d][k])
  for (int dr = wave * 16; dr < wave * 16 + 16; ++dr) {
    const unsigned short* row = Vt + ((size_t)bh * 64 + dr) * 2048 + lane * 32;
    const float* mrow = maskf + b * 2048 + lane * 32;
    float s = 0.f;
#pragma unroll
    for (int c = 0; c < 32; c += 4) {
      ushort4 v = *(const ushort4*)(row + c);
      float4 m = *(const float4*)(mrow + c);
      s += bf2f(v.x) * m.x + bf2f(v.y) * m.y + bf2f(v.z) * m.z + bf2f(v.w) * m.w;
    }
#pragma unroll
    for (int off = 32; off >= 1; off >>= 1) s += __shfl_xor(s, off);
    if (lane == 0) FullVm[bh * 64 + dr] = s;
  }
  if (wave == 0) {                    // kmaxb[bh] = max_k ksqp
    const float* kp = ksqp + bh * 2048 + lane;
    float mx = -3.0e38f;
    for (int c = 0; c < 2048; c += 64) mx = fmaxf(mx, kp[c]);
#pragma unroll
    for (int off = 32; off >= 1; off >>= 1) mx = fmaxf(mx, __shfl_xor(mx, off));
    if (lane == 0) kmaxb[bh] = mx;
  }
  if (wave == 1 && (bh == 0 || bh == 16)) {   // den_base[b] = sum m
    const float* mrow = maskf + b * 2048 + lane;
    float s = 0.f;
    for (int c = 0; c < 2048; c += 64) s += mrow[c];
#pragma unroll
    for (int off = 32; off >= 1; off >>= 1) s += __shfl_xor(s, off);
    if (lane == 0) den_base[b] = s;
  }
}

// ---------------- fused RBF attention, classify-and-skip ----------------
// grid (32 bh, 32 qtiles), 4 waves: wave = qg*2 + hf. K-only LDS staging
// (double-buffered, swizzled). Fast tiles: QK MFMA + max-test only.
__global__ __launch_bounds__(256)
void attn_kernel(const unsigned short* __restrict__ Qbf,
                 const unsigned short* __restrict__ Kbf,
                 const unsigned short* __restrict__ Vt,
                 const float* __restrict__ qsqp,
                 const float* __restrict__ ksqp,
                 const float* __restrict__ maskf,
                 const float* __restrict__ FullVm,
                 const float* __restrict__ den_base,
                 const float* __restrict__ kmaxb,
                 unsigned short* __restrict__ Obf) {
  __shared__ unsigned short Ks[2][4096];   // [buf][64 k][64 d] swizzled (chunk^=row&7)
  __shared__ float Obuf[2][32][64];
  __shared__ float Dbuf[2][64];

  const int bh = blockIdx.x;
  const int b = bh >> 4, h = bh & 15;
  const int t = threadIdx.x;
  const int wave = t >> 6, lane = t & 63;
  const int qg = wave >> 1, hf = wave & 1;
  const int li = lane & 31, hi = lane >> 5;
  const int q0 = blockIdx.y * 64 + qg * 32;
  const int qrow = q0 + li;

  // Q fragments: B-operand, lane holds Q[qrow][dblk*16 + hi*8 + e]
  const unsigned short* Qr = Qbf + (size_t)(b * 2048 + qrow) * 1024 + h * 64 + hi * 8;
  bf16x8 qf[4];
#pragma unroll
  for (int dblk = 0; dblk < 4; ++dblk) qf[dblk] = *(const bf16x8*)(Qr + dblk * 16);

  const float qsl = qsqp[bh * 2048 + qrow];
  const float thr = -14.0f - qsl - kmaxb[bh];   // st_raw > thr possible => slow path

  const unsigned short* Kbase = Kbf + (size_t)b * 2048 * 1024 + h * 64;
  const unsigned short* VtB = Vt + (size_t)bh * 64 * 2048;

  // staging: chunk p (16B) of an 8KB K tile; row = p>>3, slot cp = p&7 holds
  // logical chunk cl = cp ^ (row&7)  (read side XORs the same way).
  const int p0 = t,        r0 = p0 >> 3, c0 = (p0 & 7) ^ (r0 & 7);
  const int p1 = 256 + t,  r1 = p1 >> 3, c1 = (p1 & 7) ^ (r1 & 7);

  f32x16 oa0, oa1;
#pragma unroll
  for (int r = 0; r < 16; ++r) { oa0[r] = 0.f; oa1[r] = 0.f; }
  float den = 0.f;

#define STAGE(bi, tj)                                                                               \
  do {                                                                                              \
    const int j0s = (tj) * 64;                                                                      \
    __builtin_amdgcn_global_load_lds((gas_t)(const void*)(Kbase + (size_t)(j0s + r0) * 1024 + c0 * 8), \
                                     (las_t)(void*)(Ks[bi] + p0 * 8), 16, 0, 0);                    \
    __builtin_amdgcn_global_load_lds((gas_t)(const void*)(Kbase + (size_t)(j0s + r1) * 1024 + c1 * 8), \
                                     (las_t)(void*)(Ks[bi] + p1 * 8), 16, 0, 0);                    \
  } while (0)

  STAGE(0, 0);
  __syncthreads();

  const int jw = hf * 32;            // this wave's k-offset within the 64-k tile
  const int krow = jw + li;          // K LDS row
  const int ksw = krow & 7;

  for (int tj = 0; tj < 32; ++tj) {
    const int cur = tj & 1;
    if (tj + 1 < 32) STAGE(cur ^ 1, tj + 1);

    // QK^T raw: st = K_tile * Q^T (C-init 0); z = st + qsl + ksq'
    const unsigned short* Krow = Ks[cur] + krow * 64;
    f32x16 st;
#pragma unroll
    for (int r = 0; r < 16; ++r) st[r] = 0.f;
#pragma unroll
    for (int dblk = 0; dblk < 4; ++dblk) {
      const bf16x8 kf = *(const bf16x8*)(Krow + ((dblk * 2 + hi) ^ ksw) * 8);
      st = __builtin_amdgcn_mfma_f32_32x32x16_bf16(kf, qf[dblk], st, 0, 0, 0);
    }

    // max tree
    const float a0 = fmaxf(fmaxf(st[0], st[1]), st[2]);
    const float a1 = fmaxf(fmaxf(st[3], st[4]), st[5]);
    const float a2 = fmaxf(fmaxf(st[6], st[7]), st[8]);
    const float a3 = fmaxf(fmaxf(st[9], st[10]), st[11]);
    const float a4 = fmaxf(fmaxf(st[12], st[13]), st[14]);
    const float a5 = fmaxf(fmaxf(a0, a1), st[15]);
    const float a6 = fmaxf(fmaxf(a2, a3), a4);
    const float lmax = fmaxf(a5, a6);

    if (__any(lmax > thr)) {
      // ---- slow path (rare): ds = m * expm1(2^z), z = st + qsl + ksq' ----
      const int j0 = tj * 64 + jw;
      const float* ksb2 = ksqp + bh * 2048 + j0 + 4 * hi;
      const float* mfb2 = maskf + b * 2048 + j0 + 4 * hi;
      const float4 kq0 = *(const float4*)(ksb2);
      const float4 kq1 = *(const float4*)(ksb2 + 8);
      const float4 kq2 = *(const float4*)(ksb2 + 16);
      const float4 kq3 = *(const float4*)(ksb2 + 24);
      const float4 mf0 = *(const float4*)(mfb2);
      const float4 mf1 = *(const float4*)(mfb2 + 8);
      const float4 mf2 = *(const float4*)(mfb2 + 16);
      const float4 mf3 = *(const float4*)(mfb2 + 24);
      const float kqa[16] = {kq0.x, kq0.y, kq0.z, kq0.w, kq1.x, kq1.y, kq1.z, kq1.w,
                             kq2.x, kq2.y, kq2.z, kq2.w, kq3.x, kq3.y, kq3.z, kq3.w};
      const float mfa[16] = {mf0.x, mf0.y, mf0.z, mf0.w, mf1.x, mf1.y, mf1.z, mf1.w,
                             mf2.x, mf2.y, mf2.z, mf2.w, mf3.x, mf3.y, mf3.z, mf3.w};
      float dsv[16];
#pragma unroll
      for (int r = 0; r < 16; ++r) {
        const float z = __builtin_fminf(st[r] + qsl + kqa[r], 0.f);
        const float s = EXP2(z);
        // expm1(s)/s = 1 + s/2 + s^2/6 + s^3/24 + s^4/120
        float pl = __builtin_fmaf(s, 1.f / 120.f, 1.f / 24.f);
        pl = __builtin_fmaf(s, pl, 1.f / 6.f);
        pl = __builtin_fmaf(s, pl, 0.5f);
        pl = __builtin_fmaf(s, pl, 1.f);
        const float d_ = s * pl * mfa[r];
        dsv[r] = d_;
        den += d_;
      }

      // P redistribution: cvt_pk pairs, permlane32_swap -> B-fragments
      unsigned u00 = cvt_pk_bf16(dsv[0],  dsv[1]);
      unsigned u01 = cvt_pk_bf16(dsv[2],  dsv[3]);
      unsigned u10 = cvt_pk_bf16(dsv[4],  dsv[5]);
      unsigned u11 = cvt_pk_bf16(dsv[6],  dsv[7]);
      unsigned u20 = cvt_pk_bf16(dsv[8],  dsv[9]);
      unsigned u21 = cvt_pk_bf16(dsv[10], dsv[11]);
      unsigned u30 = cvt_pk_bf16(dsv[12], dsv[13]);
      unsigned u31 = cvt_pk_bf16(dsv[14], dsv[15]);
      permlane32_swap(u00, u10);
      permlane32_swap(u01, u11);
      permlane32_swap(u20, u30);
      permlane32_swap(u21, u31);
      union { unsigned u[4]; bf16x8 v; } pf0, pf1;
      pf0.u[0] = u00; pf0.u[1] = u01; pf0.u[2] = u10; pf0.u[3] = u11;
      pf1.u[0] = u20; pf1.u[1] = u21; pf1.u[2] = u30; pf1.u[3] = u31;

      // PV: O^T[d][q] += V^T[d][k] * dP[k][q];  V direct from global (L2-hit)
#pragma unroll
      for (int dh = 0; dh < 2; ++dh) {
        const unsigned short* Vrow = VtB + (size_t)(dh * 32 + li) * 2048 + tj * 64;
        const bf16x8 vf0 = *(const bf16x8*)(Vrow + (hf * 4 + 0 + hi) * 8);
        const bf16x8 vf1 = *(const bf16x8*)(Vrow + (hf * 4 + 2 + hi) * 8);
        if (dh == 0) {
          oa0 = __builtin_amdgcn_mfma_f32_32x32x16_bf16(vf0, pf0.v, oa0, 0, 0, 0);
          oa0 = __builtin_amdgcn_mfma_f32_32x32x16_bf16(vf1, pf1.v, oa0, 0, 0, 0);
        } else {
          oa1 = __builtin_amdgcn_mfma_f32_32x32x16_bf16(vf0, pf0.v, oa1, 0, 0, 0);
          oa1 = __builtin_amdgcn_mfma_f32_32x32x16_bf16(vf1, pf1.v, oa1, 0, 0, 0);
        }
      }
    }

    __syncthreads();   // drains stage loads; next buffer ready
  }
#undef STAGE

  // den over hi halves (within wave)
  den += __shfl_xor(den, 32);

  // combine wave pairs (hf=0/1) via LDS
  if (hf == 1) {
#pragma unroll
    for (int r = 0; r < 16; ++r) {
      Obuf[qg][r][lane]      = oa0[r];
      Obuf[qg][16 + r][lane] = oa1[r];
    }
    Dbuf[qg][lane] = den;
  }
  __syncthreads();
  if (hf == 0) {
    const float inv = 1.f / (den_base[b] + den + Dbuf[qg][lane]);
    const float* fvm = FullVm + bh * 64;
    unsigned short* orow = Obf + (size_t)(b * 2048 + qrow) * 1024 + h * 64;
#pragma unroll
    for (int dh = 0; dh < 2; ++dh)
#pragma unroll
      for (int w = 0; w < 4; ++w) {
        float v0, v1, v2, v3;
        if (dh == 0) {
          v0 = oa0[4 * w];     v1 = oa0[4 * w + 1];
          v2 = oa0[4 * w + 2]; v3 = oa0[4 * w + 3];
        } else {
          v0 = oa1[4 * w];     v1 = oa1[4 * w + 1];
          v2 = oa1[4 * w + 2]; v3 = oa1[4 * w + 3];
        }
        v0 += Obuf[qg][dh * 16 + 4 * w + 0][lane];
        v1 += Obuf[qg][dh * 16 + 4 * w + 1][lane];
        v2 += Obuf[qg][dh * 16 + 4 * w + 2][lane];
        v3 += Obuf[qg][dh * 16 + 4 * w + 3][lane];
        // d = 32*dh + 8*w + 4*hi + i
        const float4 fv = *(const float4*)(fvm + dh * 32 + w * 8 + hi * 4);
        ushort4 o4;
        o4.x = f2bf((v0 + fv.x) * inv);
        o4.y = f2bf((v1 + fv.y) * inv);
        o4.z = f2bf((v2 + fv.z) * inv);
        o4.w = f2bf((v3 + fv.w) * inv);
        *(ushort4*)(orow + dh * 32 + w * 8 + hi * 4) = o4;
      }
  }
}

extern "C" void kernel_launch(void* const* d_in, const int* in_sizes, int n_in,
                              void* d_out, int out_size, void* d_ws, size_t ws_size,
                              hipStream_t stream) {
  const float* x  = (const float*)d_in[0];
  const float* Wq = (const float*)d_in[1];
  const float* Wk = (const float*)d_in[2];
  const float* Wv = (const float*)d_in[3];
  const float* Wo = (const float*)d_in[4];
  const int* mask = (const int*)d_in[5];

  unsigned short* ws = (unsigned short*)d_ws;
  const size_t SZ = 4194304;                 // 4096*1024
  unsigned short* xbf = ws;
  unsigned short* Wbf = ws + SZ;             // Wq,Wk,Wv,Wo @ +0/+1M/+2M/+3M
  unsigned short* Qbf = ws + 2 * SZ;
  unsigned short* Kbf = ws + 3 * SZ;         // must be Qbf + SZ (gemm mode 0 relies on it)
  unsigned short* Vt  = ws + 4 * SZ;         // [bh][64][2048]
  unsigned short* Obf = ws + 5 * SZ;
  float* qsqp = (float*)(ws + 6 * SZ);
  float* ksqp = qsqp + 65536;
  float* maskf = ksqp + 65536;
  float* FullVm = maskf + 4096;
  float* den_base = FullVm + 2048;
  float* kmaxb = den_base + 2;

  // 1) f32 -> bf16 (single fused launch)
  cvt_all<<<8192, 256, 0, stream>>>(x, Wq, Wk, Wv, Wo, xbf, Wbf);

  // 2) fused QKV projection: x @ [Wq;Wk;Wv]^T  (Q prescaled by 2c)
  gemm_bt<<<dim3(32, 24), 256, 0, stream>>>(xbf, Wbf, Qbf, 1024, 0);

  // 3) -c*|q|^2 / -c*|k|^2 / mask->float
  rowsq_kernel<<<dim3(256, 2), 256, 0, stream>>>(Qbf, Kbf, mask, qsqp, ksqp, maskf);

  // 4) precompute FullVm / den_base / kmaxb
  prep_kernel<<<32, 256, 0, stream>>>(Vt, maskf, ksqp, FullVm, den_base, kmaxb);

  // 5) fused RBF attention -> Obf
  attn_kernel<<<dim3(32, 32), 256, 0, stream>>>(Qbf, Kbf, Vt, qsqp, ksqp, maskf,
                                                FullVm, den_base, kmaxb, Obf);

  // 6) output projection: Obf @ Wo^T -> f32 d_out
  gemm_bt<<<dim3(32, 8), 256, 0, stream>>>(Obf, Wbf + 3145728, d_out, 1024, 1);
}

// Round 6
// 116.583 us; speedup vs baseline: 2.9399x; 1.0609x over previous
//
#include <hip/hip_runtime.h>
#include <hip/hip_bf16.h>

// Problem constants: B=2, N=2048, E=1024, H=16, D_K=64, GAMMA=1
//   tokens M = 4096, K = 1024
//
// ws layout (ushort elems), SZ = 4096*1024 = 4194304:
//   xbf[SZ] | Wbf[SZ] (Wq,Wk,Wv,Wo @ +0/+1M/+2M/+3M) | Qbf[SZ] | Kbf[SZ]
//   | Vt[SZ] ([bh][64][2048]) | Obf[SZ]
//   | qsqp[64K f32] ksqp[64K f32] maskf[4K] FullVm[2K] den_base[2] kmaxb[32]
//
// Numerics: Qbf holds 2c*q (c = log2 e). qsqp = -c*|q|^2, ksqp = -c*|k|^2.
// z = qsqp + ksqp + 2c*qk = -c*d; sim s = 2^z = exp(-d) in [0,1].
// Softmax weight p = e^s * m  =  m + m*expm1(s).
//   O = FullVm + Sum_slow V*(m*expm1(s));  den = den_base + Sum_slow m*expm1(s)
// Tiles with max z < -14 contribute only their m-part (error < 6e-5/score).
//
// Pipeline: T4 counted-vmcnt. 3-buffer LDS ring; per-iter sync is
//   s_waitcnt vmcnt(N) lgkmcnt(0); s_barrier   (N = next tile's loads)
// so prefetch loads for t+1/t+2 stay in flight across the barrier.
// STAGE(t+2) is issued AFTER the barrier: all waves past barrier(t) have
// finished reading buf[(t-1)%3] == buf[(t+2)%3] (lgkmcnt(0) guarantees).

using bf16x8 = __attribute__((ext_vector_type(8))) __bf16;
using f32x4  = __attribute__((ext_vector_type(4))) float;
using f32x16 = __attribute__((ext_vector_type(16))) float;

typedef const __attribute__((address_space(1))) void* gas_t;
typedef __attribute__((address_space(3))) void* las_t;

#define C_LOG2E 1.4426950408889634f
#define TWO_C   2.8853900817779268f
#define NEG_INV_4C (-0.17328679513998632f)

#if __has_builtin(__builtin_amdgcn_exp2f)
#define EXP2(x) __builtin_amdgcn_exp2f(x)
#else
#define EXP2(x) __expf((x) * 0.6931471805599453f)
#endif

static __device__ __forceinline__ unsigned short f2bf(float x) {
  union { float f; unsigned u; } c; c.f = x;
  unsigned u = c.u;
  u += 0x7fffu + ((u >> 16) & 1u);          // round-to-nearest-even
  return (unsigned short)(u >> 16);
}
static __device__ __forceinline__ float bf2f(unsigned short b) {
  union { unsigned u; float f; } c; c.u = ((unsigned)b) << 16;
  return c.f;
}
static __device__ __forceinline__ unsigned cvt_pk_bf16(float lo, float hi) {
  unsigned r;
  asm("v_cvt_pk_bf16_f32 %0, %1, %2" : "=v"(r) : "v"(lo), "v"(hi));
  return r;
}
static __device__ __forceinline__ void permlane32_swap(unsigned &a, unsigned &b) {
#if __has_builtin(__builtin_amdgcn_permlane32_swap)
  auto r = __builtin_amdgcn_permlane32_swap(a, b, false, false);
  a = r[0]; b = r[1];
#else
  asm("v_permlane32_swap_b32 %0, %1" : "+v"(a), "+v"(b));
#endif
}

// counted-vmcnt barrier: wait own oldest loads (leave N newest in flight),
// drain LDS ops, then raw barrier. memory clobber orders all mem ops.
#define SYNC_VM(N)                                                           \
  do {                                                                       \
    asm volatile("s_waitcnt vmcnt(" #N ") lgkmcnt(0)\n\ts_barrier" ::: "memory"); \
    __builtin_amdgcn_sched_barrier(0);                                       \
  } while (0)

// ---------------- fused f32 -> bf16 convert for all 5 inputs ----------------
__global__ __launch_bounds__(256)
void cvt_all(const float* __restrict__ x,  const float* __restrict__ wq,
             const float* __restrict__ wk, const float* __restrict__ wv,
             const float* __restrict__ wo,
             unsigned short* __restrict__ xbf, unsigned short* __restrict__ Wbf) {
  const int idx = blockIdx.x * 256 + threadIdx.x;
  const float* src; unsigned short* dst; int off;
  if (idx < 1048576) { src = x; dst = xbf; off = idx; }
  else {
    const int r = idx - 1048576;
    const int w = r >> 18;                 // 262144 groups per W
    off = r & 262143;
    src = (w == 0) ? wq : (w == 1) ? wk : (w == 2) ? wv : wo;
    dst = Wbf + (size_t)w * 1048576u;
  }
  const float4 v = ((const float4*)src)[off];
  ushort4 o;
  o.x = f2bf(v.x); o.y = f2bf(v.y); o.z = f2bf(v.z); o.w = f2bf(v.w);
  ((ushort4*)dst)[off] = o;
}

// ---------------- GEMM: C[M][Ncols] = A[M][K] * Bt[Ncols][K]^T ----------------
// 128x128 tile, 4 waves (2x2), BK=32, global_load_lds width 16.
// 3-buffer ring + counted vmcnt: 4 loads/tile, steady wait = vmcnt(4).
__global__ __launch_bounds__(256)
void gemm_bt(const unsigned short* __restrict__ A,
             const unsigned short* __restrict__ Bt,
             void* __restrict__ out0, int Kdim, int mode) {
  __shared__ unsigned short As[3][4096];   // [buf][128][32]
  __shared__ unsigned short Bs[3][4096];
  const int t  = threadIdx.x;
  const int m0 = blockIdx.x * 128;
  const int n0 = blockIdx.y * 128;
  const int srow = t >> 2;
  const int scol = (t & 3) * 8;
  const unsigned short* pA = A  + (size_t)(m0 + srow) * Kdim + scol;
  const unsigned short* pB = Bt + (size_t)(n0 + srow) * Kdim + scol;
  const size_t rowskip = (size_t)64 * Kdim;

  const int wave = t >> 6, lane = t & 63;
  const int wm = (wave >> 1) * 64, wn = (wave & 1) * 64;
  const int fr = lane & 15, fg = lane >> 4;
  const int aoff = (wm + fr) * 32 + fg * 8;
  const int boff = (wn + fr) * 32 + fg * 8;

  f32x4 acc[4][4];
#pragma unroll
  for (int mi = 0; mi < 4; ++mi)
#pragma unroll
    for (int ni = 0; ni < 4; ++ni)
      acc[mi][ni] = (f32x4){0.f, 0.f, 0.f, 0.f};

#define GSTAGE(bi, kk)                                                                                  \
  do {                                                                                                  \
    const int kc = (kk) * 32;                                                                           \
    __builtin_amdgcn_global_load_lds((gas_t)(const void*)(pA + kc),           (las_t)(void*)(As[bi] + t * 8),        16, 0, 0); \
    __builtin_amdgcn_global_load_lds((gas_t)(const void*)(pA + kc + rowskip), (las_t)(void*)(As[bi] + 2048 + t * 8), 16, 0, 0); \
    __builtin_amdgcn_global_load_lds((gas_t)(const void*)(pB + kc),           (las_t)(void*)(Bs[bi] + t * 8),        16, 0, 0); \
    __builtin_amdgcn_global_load_lds((gas_t)(const void*)(pB + kc + rowskip), (las_t)(void*)(Bs[bi] + 2048 + t * 8), 16, 0, 0); \
  } while (0)

  const int NK = Kdim >> 5;
  GSTAGE(0, 0);
  GSTAGE(1, 1);

  for (int ks = 0; ks < NK; ++ks) {
    const int cur = ks % 3;
    if (ks + 1 < NK) SYNC_VM(4); else SYNC_VM(0);
    if (ks + 2 < NK) GSTAGE((ks + 2) % 3, ks + 2);

    bf16x8 af[4], bfr[4];
#pragma unroll
    for (int mi = 0; mi < 4; ++mi) af[mi]  = *(const bf16x8*)(As[cur] + aoff + mi * 512);
#pragma unroll
    for (int ni = 0; ni < 4; ++ni) bfr[ni] = *(const bf16x8*)(Bs[cur] + boff + ni * 512);
#pragma unroll
    for (int mi = 0; mi < 4; ++mi)
#pragma unroll
      for (int ni = 0; ni < 4; ++ni)
        acc[mi][ni] = __builtin_amdgcn_mfma_f32_16x16x32_bf16(af[mi], bfr[ni], acc[mi][ni], 0, 0, 0);
  }
#undef GSTAGE

  // epilogue: C/D layout col = lane&15, row = (lane>>4)*4 + r  [m89-verified]
#pragma unroll
  for (int mi = 0; mi < 4; ++mi) {
    const int gm = m0 + wm + mi * 16 + fg * 4;
#pragma unroll
    for (int ni = 0; ni < 4; ++ni) {
      const int gn = n0 + wn + ni * 16 + fr;
      if (mode == 0) {
        unsigned short* outw = (unsigned short*)out0;
        const int z = gn >> 10, col = gn & 1023;
        if (z < 2) {                                   // Q (scaled by 2c) or K
          const float sc = (z == 0) ? TWO_C : 1.0f;
          unsigned short* dst = outw + (size_t)z * 4194304u;
#pragma unroll
          for (int r = 0; r < 4; ++r)
            dst[(size_t)(gm + r) * 1024 + col] = f2bf(acc[mi][ni][r] * sc);
        } else {                                       // V -> Vt[bh][d][n]
          ushort4 o4;
          o4.x = f2bf(acc[mi][ni][0]); o4.y = f2bf(acc[mi][ni][1]);
          o4.z = f2bf(acc[mi][ni][2]); o4.w = f2bf(acc[mi][ni][3]);
          const int bb = gm >> 11, nn = gm & 2047;
          const int hh = col >> 6, dd = col & 63;
          unsigned short* vt = outw + (size_t)2 * 4194304u;
          *(ushort4*)(vt + ((size_t)((bb * 16 + hh) * 64 + dd)) * 2048 + nn) = o4;
        }
      } else {                                         // f32 out
        float* dst = (float*)out0;
#pragma unroll
        for (int r = 0; r < 4; ++r)
          dst[(size_t)(gm + r) * 1024 + gn] = acc[mi][ni][r];
      }
    }
  }
}

// ---------------- per-(bh,n) scaled row sumsq + mask->float + inits ----------------
__global__ __launch_bounds__(256)
void rowsq_kernel(const unsigned short* __restrict__ Qbf,
                  const unsigned short* __restrict__ Kbf,
                  const int* __restrict__ mask,
                  float* __restrict__ qsqp, float* __restrict__ ksqp,
                  float* __restrict__ maskf,
                  float* __restrict__ FullVm,
                  float* __restrict__ den_base,
                  unsigned* __restrict__ kmax_bits) {
  const int tid = blockIdx.x * 256 + threadIdx.x;     // 0..65535 = bh*2048 + n
  const int kpath = blockIdx.y;
  const unsigned short* src = (kpath == 0) ? Qbf : Kbf;
  const int bh = tid >> 11, n = tid & 2047;
  const int b = bh >> 4, h = bh & 15;
  const unsigned short* row = src + (size_t)(b * 2048 + n) * 1024 + h * 64;
  float s = 0.f;
#pragma unroll
  for (int c = 0; c < 64; c += 4) {
    ushort4 v = *(const ushort4*)(row + c);
    float f0 = bf2f(v.x), f1 = bf2f(v.y), f2 = bf2f(v.z), f3 = bf2f(v.w);
    s += f0 * f0 + f1 * f1 + f2 * f2 + f3 * f3;
  }
  if (kpath == 0) {
    qsqp[tid] = s * NEG_INV_4C;      // Q was prescaled by 2c: -c*|q|^2 = -s/(4c)
    if (tid < 2048) FullVm[tid] = 0.f;               // init for prep2 atomics
    if (tid < 32) kmax_bits[tid] = 0xFF800000u;      // -inf bits (uint-min trick)
    if (tid < 2) den_base[tid] = 0.f;
  } else {
    ksqp[tid] = s * (-C_LOG2E);
    if (tid < 4096) maskf[tid] = (mask[tid] == 0) ? 0.f : 1.f;
  }
}

// ---------------- parallel precompute: FullVm / kmax / den_base ----------------
// grid (32 bh, 8 kchunks). kmax via uint-min on negative-float bit patterns.
__global__ __launch_bounds__(256)
void prep2_kernel(const unsigned short* __restrict__ Vt,
                  const float* __restrict__ maskf,
                  const float* __restrict__ ksqp,
                  float* __restrict__ FullVm,
                  float* __restrict__ den_base,
                  unsigned* __restrict__ kmax_bits) {
  const int bh = blockIdx.x, c = blockIdx.y;
  const int b = bh >> 4;
  const int wave = threadIdx.x >> 6, lane = threadIdx.x & 63;
  const int k0 = c * 256;
  const float4 mv = *(const float4*)(maskf + b * 2048 + k0 + lane * 4);
#pragma unroll 4
  for (int dr = wave * 16; dr < wave * 16 + 16; ++dr) {
    const ushort4 v = *(const ushort4*)(Vt + ((size_t)bh * 64 + dr) * 2048 + k0 + lane * 4);
    float s = bf2f(v.x) * mv.x + bf2f(v.y) * mv.y + bf2f(v.z) * mv.z + bf2f(v.w) * mv.w;
#pragma unroll
    for (int off = 32; off >= 1; off >>= 1) s += __shfl_xor(s, off);
    if (lane == 0) atomicAdd(&FullVm[bh * 64 + dr], s);
  }
  if (wave == 0) {   // max of ksqp chunk (all values <= -0.0): float-max == uint-min
    const float4 kq = *(const float4*)(ksqp + bh * 2048 + k0 + lane * 4);
    float mx = fmaxf(fmaxf(kq.x, kq.y), fmaxf(kq.z, kq.w));
#pragma unroll
    for (int off = 32; off >= 1; off >>= 1) mx = fmaxf(mx, __shfl_xor(mx, off));
    if (lane == 0) atomicMin(&kmax_bits[bh], __float_as_uint(mx));
  }
  if (wave == 1 && (bh & 15) == 0) {
    float s = mv.x + mv.y + mv.z + mv.w;
#pragma unroll
    for (int off = 32; off >= 1; off >>= 1) s += __shfl_xor(s, off);
    if (lane == 0) atomicAdd(&den_base[b], s);
  }
}

// ---------------- fused RBF attention, classify-and-skip ----------------
// grid (32 bh, 32 qtiles), 4 waves: wave = qg*2 + hf. K-only LDS staging,
// 3-buffer ring + counted vmcnt (2 loads/tile -> steady wait vmcnt(2)).
// Fast tiles: QK MFMA + max-test only. Obuf aliases the K ring post-loop.
__global__ __launch_bounds__(256)
void attn_kernel(const unsigned short* __restrict__ Qbf,
                 const unsigned short* __restrict__ Kbf,
                 const unsigned short* __restrict__ Vt,
                 const float* __restrict__ qsqp,
                 const float* __restrict__ ksqp,
                 const float* __restrict__ maskf,
                 const float* __restrict__ FullVm,
                 const float* __restrict__ den_base,
                 const float* __restrict__ kmaxb,
                 unsigned short* __restrict__ Obf) {
  __shared__ unsigned short Ks[3][4096];   // [buf][64 k][64 d] swizzled (chunk^=row&7)

  const int bh = blockIdx.x;
  const int b = bh >> 4, h = bh & 15;
  const int t = threadIdx.x;
  const int wave = t >> 6, lane = t & 63;
  const int qg = wave >> 1, hf = wave & 1;
  const int li = lane & 31, hi = lane >> 5;
  const int q0 = blockIdx.y * 64 + qg * 32;
  const int qrow = q0 + li;

  // Q fragments: B-operand, lane holds Q[qrow][dblk*16 + hi*8 + e]
  const unsigned short* Qr = Qbf + (size_t)(b * 2048 + qrow) * 1024 + h * 64 + hi * 8;
  bf16x8 qf[4];
#pragma unroll
  for (int dblk = 0; dblk < 4; ++dblk) qf[dblk] = *(const bf16x8*)(Qr + dblk * 16);

  const float qsl = qsqp[bh * 2048 + qrow];
  const float thr = -14.0f - qsl - kmaxb[bh];   // st_raw > thr possible => slow path

  const unsigned short* Kbase = Kbf + (size_t)b * 2048 * 1024 + h * 64;
  const unsigned short* VtB = Vt + (size_t)bh * 64 * 2048;

  // staging: chunk p (16B) of an 8KB K tile; row = p>>3, slot cp = p&7 holds
  // logical chunk cl = cp ^ (row&7)  (read side XORs the same way).
  const int p0 = t,        r0 = p0 >> 3, c0 = (p0 & 7) ^ (r0 & 7);
  const int p1 = 256 + t,  r1 = p1 >> 3, c1 = (p1 & 7) ^ (r1 & 7);

  f32x16 oa0, oa1;
#pragma unroll
  for (int r = 0; r < 16; ++r) { oa0[r] = 0.f; oa1[r] = 0.f; }
  float den = 0.f;

#define STAGE(bi, tj)                                                                               \
  do {                                                                                              \
    const int j0s = (tj) * 64;                                                                      \
    __builtin_amdgcn_global_load_lds((gas_t)(const void*)(Kbase + (size_t)(j0s + r0) * 1024 + c0 * 8), \
                                     (las_t)(void*)(Ks[bi] + p0 * 8), 16, 0, 0);                    \
    __builtin_amdgcn_global_load_lds((gas_t)(const void*)(Kbase + (size_t)(j0s + r1) * 1024 + c1 * 8), \
                                     (las_t)(void*)(Ks[bi] + p1 * 8), 16, 0, 0);                    \
  } while (0)

  STAGE(0, 0);
  STAGE(1, 1);

  const int jw = hf * 32;            // this wave's k-offset within the 64-k tile
  const int krow = jw + li;          // K LDS row
  const int ksw = krow & 7;

  for (int tj = 0; tj < 32; ++tj) {
    const int cur = tj % 3;
    if (tj + 1 < 32) SYNC_VM(2); else SYNC_VM(0);
    if (tj + 2 < 32) STAGE((tj + 2) % 3, tj + 2);

    // QK^T raw: st = K_tile * Q^T (C-init 0); z = st + qsl + ksq'
    const unsigned short* Krow = Ks[cur] + krow * 64;
    f32x16 st;
#pragma unroll
    for (int r = 0; r < 16; ++r) st[r] = 0.f;
#pragma unroll
    for (int dblk = 0; dblk < 4; ++dblk) {
      const bf16x8 kf = *(const bf16x8*)(Krow + ((dblk * 2 + hi) ^ ksw) * 8);
      st = __builtin_amdgcn_mfma_f32_32x32x16_bf16(kf, qf[dblk], st, 0, 0, 0);
    }

    // max tree
    const float a0 = fmaxf(fmaxf(st[0], st[1]), st[2]);
    const float a1 = fmaxf(fmaxf(st[3], st[4]), st[5]);
    const float a2 = fmaxf(fmaxf(st[6], st[7]), st[8]);
    const float a3 = fmaxf(fmaxf(st[9], st[10]), st[11]);
    const float a4 = fmaxf(fmaxf(st[12], st[13]), st[14]);
    const float a5 = fmaxf(fmaxf(a0, a1), st[15]);
    const float a6 = fmaxf(fmaxf(a2, a3), a4);
    const float lmax = fmaxf(a5, a6);

    if (__any(lmax > thr)) {
      // ---- slow path (rare): ds = m * expm1(2^z), z = st + qsl + ksq' ----
      const int j0 = tj * 64 + jw;
      const float* ksb2 = ksqp + bh * 2048 + j0 + 4 * hi;
      const float* mfb2 = maskf + b * 2048 + j0 + 4 * hi;
      const float4 kq0 = *(const float4*)(ksb2);
      const float4 kq1 = *(const float4*)(ksb2 + 8);
      const float4 kq2 = *(const float4*)(ksb2 + 16);
      const float4 kq3 = *(const float4*)(ksb2 + 24);
      const float4 mf0 = *(const float4*)(mfb2);
      const float4 mf1 = *(const float4*)(mfb2 + 8);
      const float4 mf2 = *(const float4*)(mfb2 + 16);
      const float4 mf3 = *(const float4*)(mfb2 + 24);
      const float kqa[16] = {kq0.x, kq0.y, kq0.z, kq0.w, kq1.x, kq1.y, kq1.z, kq1.w,
                             kq2.x, kq2.y, kq2.z, kq2.w, kq3.x, kq3.y, kq3.z, kq3.w};
      const float mfa[16] = {mf0.x, mf0.y, mf0.z, mf0.w, mf1.x, mf1.y, mf1.z, mf1.w,
                             mf2.x, mf2.y, mf2.z, mf2.w, mf3.x, mf3.y, mf3.z, mf3.w};
      float dsv[16];
#pragma unroll
      for (int r = 0; r < 16; ++r) {
        const float z = __builtin_fminf(st[r] + qsl + kqa[r], 0.f);
        const float s = EXP2(z);
        // expm1(s)/s = 1 + s/2 + s^2/6 + s^3/24 + s^4/120
        float pl = __builtin_fmaf(s, 1.f / 120.f, 1.f / 24.f);
        pl = __builtin_fmaf(s, pl, 1.f / 6.f);
        pl = __builtin_fmaf(s, pl, 0.5f);
        pl = __builtin_fmaf(s, pl, 1.f);
        const float d_ = s * pl * mfa[r];
        dsv[r] = d_;
        den += d_;
      }

      // P redistribution: cvt_pk pairs, permlane32_swap -> B-fragments
      unsigned u00 = cvt_pk_bf16(dsv[0],  dsv[1]);
      unsigned u01 = cvt_pk_bf16(dsv[2],  dsv[3]);
      unsigned u10 = cvt_pk_bf16(dsv[4],  dsv[5]);
      unsigned u11 = cvt_pk_bf16(dsv[6],  dsv[7]);
      unsigned u20 = cvt_pk_bf16(dsv[8],  dsv[9]);
      unsigned u21 = cvt_pk_bf16(dsv[10], dsv[11]);
      unsigned u30 = cvt_pk_bf16(dsv[12], dsv[13]);
      unsigned u31 = cvt_pk_bf16(dsv[14], dsv[15]);
      permlane32_swap(u00, u10);
      permlane32_swap(u01, u11);
      permlane32_swap(u20, u30);
      permlane32_swap(u21, u31);
      union { unsigned u[4]; bf16x8 v; } pf0, pf1;
      pf0.u[0] = u00; pf0.u[1] = u01; pf0.u[2] = u10; pf0.u[3] = u11;
      pf1.u[0] = u20; pf1.u[1] = u21; pf1.u[2] = u30; pf1.u[3] = u31;

      // PV: O^T[d][q] += V^T[d][k] * dP[k][q];  V direct from global (L2-hit)
#pragma unroll
      for (int dh = 0; dh < 2; ++dh) {
        const unsigned short* Vrow = VtB + (size_t)(dh * 32 + li) * 2048 + tj * 64;
        const bf16x8 vf0 = *(const bf16x8*)(Vrow + (hf * 4 + 0 + hi) * 8);
        const bf16x8 vf1 = *(const bf16x8*)(Vrow + (hf * 4 + 2 + hi) * 8);
        if (dh == 0) {
          oa0 = __builtin_amdgcn_mfma_f32_32x32x16_bf16(vf0, pf0.v, oa0, 0, 0, 0);
          oa0 = __builtin_amdgcn_mfma_f32_32x32x16_bf16(vf1, pf1.v, oa0, 0, 0, 0);
        } else {
          oa1 = __builtin_amdgcn_mfma_f32_32x32x16_bf16(vf0, pf0.v, oa1, 0, 0, 0);
          oa1 = __builtin_amdgcn_mfma_f32_32x32x16_bf16(vf1, pf1.v, oa1, 0, 0, 0);
        }
      }
    }
  }
#undef STAGE

  // den over hi halves (within wave)
  den += __shfl_xor(den, 32);

  // combine wave pairs (hf=0/1); Obuf/Dbuf alias the (now dead) K ring
  __syncthreads();
  float* Obuf = (float*)&Ks[0][0];          // [2 qg][32 slot][64 lane] = 16KB
  float* Dbuf = (float*)&Ks[0][0] + 4096;   // [2 qg][64 lane]
  if (hf == 1) {
#pragma unroll
    for (int r = 0; r < 16; ++r) {
      Obuf[(qg * 32 + r) * 64 + lane]      = oa0[r];
      Obuf[(qg * 32 + 16 + r) * 64 + lane] = oa1[r];
    }
    Dbuf[qg * 64 + lane] = den;
  }
  __syncthreads();
  if (hf == 0) {
    const float inv = 1.f / (den_base[b] + den + Dbuf[qg * 64 + lane]);
    const float* fvm = FullVm + bh * 64;
    unsigned short* orow = Obf + (size_t)(b * 2048 + qrow) * 1024 + h * 64;
#pragma unroll
    for (int dh = 0; dh < 2; ++dh)
#pragma unroll
      for (int w = 0; w < 4; ++w) {
        float v0, v1, v2, v3;
        if (dh == 0) {
          v0 = oa0[4 * w];     v1 = oa0[4 * w + 1];
          v2 = oa0[4 * w + 2]; v3 = oa0[4 * w + 3];
        } else {
          v0 = oa1[4 * w];     v1 = oa1[4 * w + 1];
          v2 = oa1[4 * w + 2]; v3 = oa1[4 * w + 3];
        }
        const int sbase = (qg * 32 + dh * 16 + 4 * w) * 64 + lane;
        v0 += Obuf[sbase];       v1 += Obuf[sbase + 64];
        v2 += Obuf[sbase + 128]; v3 += Obuf[sbase + 192];
        // d = 32*dh + 8*w + 4*hi + i
        const float4 fv = *(const float4*)(fvm + dh * 32 + w * 8 + hi * 4);
        ushort4 o4;
        o4.x = f2bf((v0 + fv.x) * inv);
        o4.y = f2bf((v1 + fv.y) * inv);
        o4.z = f2bf((v2 + fv.z) * inv);
        o4.w = f2bf((v3 + fv.w) * inv);
        *(ushort4*)(orow + dh * 32 + w * 8 + hi * 4) = o4;
      }
  }
}

extern "C" void kernel_launch(void* const* d_in, const int* in_sizes, int n_in,
                              void* d_out, int out_size, void* d_ws, size_t ws_size,
                              hipStream_t stream) {
  const float* x  = (const float*)d_in[0];
  const float* Wq = (const float*)d_in[1];
  const float* Wk = (const float*)d_in[2];
  const float* Wv = (const float*)d_in[3];
  const float* Wo = (const float*)d_in[4];
  const int* mask = (const int*)d_in[5];

  unsigned short* ws = (unsigned short*)d_ws;
  const size_t SZ = 4194304;                 // 4096*1024
  unsigned short* xbf = ws;
  unsigned short* Wbf = ws + SZ;             // Wq,Wk,Wv,Wo @ +0/+1M/+2M/+3M
  unsigned short* Qbf = ws + 2 * SZ;
  unsigned short* Kbf = ws + 3 * SZ;         // must be Qbf + SZ (gemm mode 0 relies on it)
  unsigned short* Vt  = ws + 4 * SZ;         // [bh][64][2048]
  unsigned short* Obf = ws + 5 * SZ;
  float* qsqp = (float*)(ws + 6 * SZ);
  float* ksqp = qsqp + 65536;
  float* maskf = ksqp + 65536;
  float* FullVm = maskf + 4096;
  float* den_base = FullVm + 2048;
  float* kmaxb = den_base + 2;               // also used as unsigned bits

  // 1) f32 -> bf16 (single fused launch)
  cvt_all<<<8192, 256, 0, stream>>>(x, Wq, Wk, Wv, Wo, xbf, Wbf);

  // 2) fused QKV projection: x @ [Wq;Wk;Wv]^T  (Q prescaled by 2c)
  gemm_bt<<<dim3(32, 24), 256, 0, stream>>>(xbf, Wbf, Qbf, 1024, 0);

  // 3) -c*|q|^2 / -c*|k|^2 / mask->float / init accumulators
  rowsq_kernel<<<dim3(256, 2), 256, 0, stream>>>(Qbf, Kbf, mask, qsqp, ksqp, maskf,
                                                 FullVm, den_base, (unsigned*)kmaxb);

  // 4) parallel precompute FullVm / kmax / den_base
  prep2_kernel<<<dim3(32, 8), 256, 0, stream>>>(Vt, maskf, ksqp, FullVm, den_base,
                                                (unsigned*)kmaxb);

  // 5) fused RBF attention -> Obf
  attn_kernel<<<dim3(32, 32), 256, 0, stream>>>(Qbf, Kbf, Vt, qsqp, ksqp, maskf,
                                                FullVm, den_base, kmaxb, Obf);

  // 6) output projection: Obf @ Wo^T -> f32 d_out
  gemm_bt<<<dim3(32, 8), 256, 0, stream>>>(Obf, Wbf + 3145728, d_out, 1024, 1);
}